// Round 1
// baseline (14239.996 us; speedup 1.0000x reference)
//
#include <hip/hip_runtime.h>
#include <math.h>

#define NN 512
#define BB 32
#define TT 12
#define HH 12
#define UU 64
#define MM 5
#define CAP 128
#define SMAXC (512 * 4096)   // slot stride in Xbuf (floats)

// ---------------- ELL build: one wave per row, deterministic compaction ---------
__global__ __launch_bounds__(256) void build_ell(const float* __restrict__ supports,
                                                 int* __restrict__ eidx,
                                                 float* __restrict__ eval_,
                                                 int* __restrict__ ecnt) {
    int wave = (blockIdx.x * blockDim.x + threadIdx.x) >> 6;
    int lane = threadIdx.x & 63;
    if (wave >= 2 * NN) return;
    const float* row = supports + (size_t)wave * NN;
    int base = 0;
    for (int k = 0; k < NN / 64; ++k) {
        float v = row[k * 64 + lane];
        unsigned long long m = __ballot(v != 0.0f);
        int pre = __popcll(m & ((1ull << lane) - 1ull));
        if (v != 0.0f) {
            int pos = base + pre;
            if (pos < CAP) {
                eidx[wave * CAP + pos] = k * 64 + lane;
                eval_[wave * CAP + pos] = v;
            }
        }
        base += __popcll(m);
    }
    if (lane == 0) ecnt[wave] = base < CAP ? base : CAP;
}

// ---------------- zero init ----------------------------------------------------
__global__ void zero_kernel(float* __restrict__ p, int n) {
    int i = blockIdx.x * 256 + threadIdx.x;
    if (i < n) p[i] = 0.0f;
}

// ---------------- concat builders ----------------------------------------------
// X0 slot0 of Xbuf: (N, B*C) with element [n][b*C+c]
__global__ void build_x0_l0(float* __restrict__ X0, const float* __restrict__ x, // (B,N)
                            const float* __restrict__ h,                         // (N,B,U)
                            const float* __restrict__ r) {                       // (N,B,2U) or null
    int idx = blockIdx.x * 256 + threadIdx.x;
    const int total = NN * BB * 65;
    if (idx >= total) return;
    int n = idx / (BB * 65);
    int rem = idx - n * (BB * 65);
    int b = rem / 65;
    int c = rem - b * 65;
    float v;
    if (c == 0) {
        v = x[b * NN + n];
    } else {
        int u = c - 1;
        v = h[((size_t)n * BB + b) * UU + u];
        if (r) v *= r[((size_t)n * BB + b) * (2 * UU) + u];
    }
    X0[idx] = v;
}

__global__ void build_x0_l1(float* __restrict__ X0, const float* __restrict__ h0,
                            const float* __restrict__ h1, const float* __restrict__ r) {
    int idx = blockIdx.x * 256 + threadIdx.x;
    const int total = NN * BB * 128;
    if (idx >= total) return;
    int n = idx >> 12;       // BB*128 = 4096
    int rem = idx & 4095;
    int b = rem >> 7;
    int c = rem & 127;
    float v;
    if (c < UU) {
        v = h0[((size_t)n * BB + b) * UU + c];
    } else {
        int u = c - UU;
        v = h1[((size_t)n * BB + b) * UU + u];
        if (r) v *= r[((size_t)n * BB + b) * (2 * UU) + u];
    }
    X0[idx] = v;
}

// ---------------- SpMM pair: both supports in one launch ------------------------
// phase 0: X[1+2s] = S_s @ X[0]
// phase 1: X[2+2s] = 2 * S_s @ X[1+2s] - X[0]
__global__ __launch_bounds__(256) void spmm_pair(float* __restrict__ Xbuf,
                                                 const int* __restrict__ eidx,
                                                 const float* __restrict__ eval_,
                                                 const int* __restrict__ ecnt,
                                                 int F, int phase) {
    __shared__ int sj[CAP];
    __shared__ float sv[CAP];
    int s = blockIdx.z;
    int i = blockIdx.x;
    int row = s * NN + i;
    int cnt = ecnt[row];
    for (int k = threadIdx.x; k < cnt; k += 256) {
        sj[k] = eidx[row * CAP + k];
        sv[k] = eval_[row * CAP + k];
    }
    __syncthreads();
    int f = blockIdx.y * 256 + threadIdx.x;
    if (f >= F) return;
    const float* X = Xbuf + (phase ? (size_t)(1 + 2 * s) * SMAXC : 0);
    float acc = 0.0f;
    for (int k = 0; k < cnt; ++k) acc += sv[k] * X[(size_t)sj[k] * F + f];
    float res;
    if (phase) res = 2.0f * acc - Xbuf[(size_t)i * F + f];
    else       res = acc;
    float* Y = Xbuf + (size_t)(phase ? (2 + 2 * s) : (1 + 2 * s)) * SMAXC;
    Y[(size_t)i * F + f] = res;
}

// ---------------- weight GEMM + bias + activation -------------------------------
// out[r=(n*B+b)][o] = act( sum_m sum_c Xbuf[m][n][b*C+c] * W[c*5+m][o] + bias[o] )
__global__ __launch_bounds__(256) void wgemm_act(const float* __restrict__ Xbuf,
                                                 const float* __restrict__ W,
                                                 const float* __restrict__ bias,
                                                 float* __restrict__ out,
                                                 int C, int F, int Ototal, int act) {
    __shared__ float At[64][33];
    __shared__ float Wt[32][64];
    int r0 = blockIdx.x * 64;
    int o0 = blockIdx.y * 64;
    int tid = threadIdx.x;
    int tx = tid & 15, ty = tid >> 4;
    float acc[4][4] = {{0.f}};
    for (int m = 0; m < MM; ++m) {
        const float* Xm = Xbuf + (size_t)m * SMAXC;
        for (int c0 = 0; c0 < C; c0 += 32) {
            #pragma unroll
            for (int l = 0; l < 8; ++l) {
                int e = tid + l * 256;
                int rr = e >> 5, kk = e & 31;
                int c = c0 + kk;
                int r = r0 + rr;
                int n = r >> 5, b = r & 31;
                At[rr][kk] = (c < C) ? Xm[(size_t)n * F + b * C + c] : 0.0f;
            }
            #pragma unroll
            for (int l = 0; l < 8; ++l) {
                int e = tid + l * 256;
                int kk = e >> 6, oo = e & 63;
                int c = c0 + kk;
                Wt[kk][oo] = (c < C) ? W[(size_t)(c * MM + m) * Ototal + o0 + oo] : 0.0f;
            }
            __syncthreads();
            #pragma unroll
            for (int kk = 0; kk < 32; ++kk) {
                float a[4], w[4];
                #pragma unroll
                for (int i = 0; i < 4; ++i) a[i] = At[ty * 4 + i][kk];
                #pragma unroll
                for (int j = 0; j < 4; ++j) w[j] = Wt[kk][tx * 4 + j];
                #pragma unroll
                for (int i = 0; i < 4; ++i)
                    #pragma unroll
                    for (int j = 0; j < 4; ++j) acc[i][j] += a[i] * w[j];
            }
            __syncthreads();
        }
    }
    #pragma unroll
    for (int i = 0; i < 4; ++i) {
        int r = r0 + ty * 4 + i;
        #pragma unroll
        for (int j = 0; j < 4; ++j) {
            int o = o0 + tx * 4 + j;
            float v = acc[i][j] + bias[o];
            if (act == 0) v = 1.0f / (1.0f + expf(-v));
            else          v = tanhf(v);
            out[(size_t)r * Ototal + o] = v;
        }
    }
}

// ---------------- GRU state update ----------------------------------------------
__global__ void gru_update(float* __restrict__ h, const float* __restrict__ g,
                           const float* __restrict__ c) {
    int idx = blockIdx.x * 256 + threadIdx.x;
    if (idx >= NN * BB * UU) return;
    int nb = idx >> 6;
    int u = idx & 63;
    float ug = g[(size_t)nb * (2 * UU) + UU + u];
    float hv = h[idx];
    h[idx] = ug * hv + (1.0f - ug) * c[idx];
}

// ---------------- projection ----------------------------------------------------
__global__ void proj_kernel(const float* __restrict__ h1, const float* __restrict__ pW,
                            const float* __restrict__ pb, float* __restrict__ outt) {
    int idx = blockIdx.x * 256 + threadIdx.x;   // B*N threads
    if (idx >= NN * BB) return;
    int b = idx >> 9;
    int n = idx & 511;
    const float* hp = h1 + ((size_t)n * BB + b) * UU;
    float acc = pb[0];
    #pragma unroll 8
    for (int u = 0; u < UU; ++u) acc += hp[u] * pW[u];
    outt[b * NN + n] = acc;
}

// ================================================================================
extern "C" void kernel_launch(void* const* d_in, const int* in_sizes, int n_in,
                              void* d_out, int out_size, void* d_ws, size_t ws_size,
                              hipStream_t stream) {
    const float* inputs   = (const float*)d_in[0];
    const float* supports = (const float*)d_in[1];
    const float* enc0_Wg = (const float*)d_in[2];
    const float* enc0_bg = (const float*)d_in[3];
    const float* enc0_Wc = (const float*)d_in[4];
    const float* enc0_bc = (const float*)d_in[5];
    const float* enc1_Wg = (const float*)d_in[6];
    const float* enc1_bg = (const float*)d_in[7];
    const float* enc1_Wc = (const float*)d_in[8];
    const float* enc1_bc = (const float*)d_in[9];
    const float* dec0_Wg = (const float*)d_in[10];
    const float* dec0_bg = (const float*)d_in[11];
    const float* dec0_Wc = (const float*)d_in[12];
    const float* dec0_bc = (const float*)d_in[13];
    const float* dec1_Wg = (const float*)d_in[14];
    const float* dec1_bg = (const float*)d_in[15];
    const float* dec1_Wc = (const float*)d_in[16];
    const float* dec1_bc = (const float*)d_in[17];
    const float* projW   = (const float*)d_in[18];
    const float* projb   = (const float*)d_in[19];
    float* out = (float*)d_out;

    char* wsb = (char*)d_ws;
    size_t off = 0;
    auto alloc = [&](size_t bytes) -> char* {
        char* p = wsb + off;
        off = (off + bytes + 255) & ~(size_t)255;
        return p;
    };
    int*   eidx  = (int*)alloc((size_t)2 * NN * CAP * 4);
    float* eval_ = (float*)alloc((size_t)2 * NN * CAP * 4);
    int*   ecnt  = (int*)alloc((size_t)2 * NN * 4);
    float* h0    = (float*)alloc((size_t)NN * BB * UU * 4);
    float* h1    = (float*)alloc((size_t)NN * BB * UU * 4);
    float* xzero = (float*)alloc((size_t)NN * BB * 4);
    float* g     = (float*)alloc((size_t)NN * BB * 2 * UU * 4);
    float* cb    = (float*)alloc((size_t)NN * BB * UU * 4);
    float* Xbuf  = (float*)alloc((size_t)5 * SMAXC * 4);
    if (off > ws_size) return;   // workspace too small -> will fail validation loudly

    // preprocessing
    build_ell<<<256, 256, 0, stream>>>(supports, eidx, eval_, ecnt);
    {
        int nz = NN * BB * UU * 2 + NN * BB;  // h0, h1, xzero are contiguous
        zero_kernel<<<(nz + 255) / 256, 256, 0, stream>>>(h0, nz);
    }

    auto diffusion = [&](int F) {
        dim3 gr(NN, (F + 255) / 256, 2);
        spmm_pair<<<gr, 256, 0, stream>>>(Xbuf, eidx, eval_, ecnt, F, 0);
        spmm_pair<<<gr, 256, 0, stream>>>(Xbuf, eidx, eval_, ecnt, F, 1);
    };
    auto wg = [&](const float* Wp, const float* bp, float* outp, int C, int O, int act) {
        dim3 gr(NN * BB / 64, O / 64);
        wgemm_act<<<gr, 256, 0, stream>>>(Xbuf, Wp, bp, outp, C, C * BB, O, act);
    };
    auto cell_l0 = [&](const float* x_bn, float* h, const float* Wgp, const float* bgp,
                       const float* Wcp, const float* bcp) {
        const int tot = NN * BB * 65;
        build_x0_l0<<<(tot + 255) / 256, 256, 0, stream>>>(Xbuf, x_bn, h, nullptr);
        diffusion(BB * 65);
        wg(Wgp, bgp, g, 65, 2 * UU, 0);
        build_x0_l0<<<(tot + 255) / 256, 256, 0, stream>>>(Xbuf, x_bn, h, g);
        diffusion(BB * 65);
        wg(Wcp, bcp, cb, 65, UU, 1);
        gru_update<<<NN * BB * UU / 256, 256, 0, stream>>>(h, g, cb);
    };
    auto cell_l1 = [&](const float* hin, float* h, const float* Wgp, const float* bgp,
                       const float* Wcp, const float* bcp) {
        const int tot = NN * BB * 128;
        build_x0_l1<<<(tot + 255) / 256, 256, 0, stream>>>(Xbuf, hin, h, nullptr);
        diffusion(BB * 128);
        wg(Wgp, bgp, g, 128, 2 * UU, 0);
        build_x0_l1<<<(tot + 255) / 256, 256, 0, stream>>>(Xbuf, hin, h, g);
        diffusion(BB * 128);
        wg(Wcp, bcp, cb, 128, UU, 1);
        gru_update<<<NN * BB * UU / 256, 256, 0, stream>>>(h, g, cb);
    };

    // encoder
    for (int t = 0; t < TT; ++t) {
        cell_l0(inputs + (size_t)t * BB * NN, h0, enc0_Wg, enc0_bg, enc0_Wc, enc0_bc);
        cell_l1(h0, h1, enc1_Wg, enc1_bg, enc1_Wc, enc1_bc);
    }
    // decoder
    for (int t = 0; t < HH; ++t) {
        const float* xin = (t == 0) ? xzero : (out + (size_t)(t - 1) * BB * NN);
        cell_l0(xin, h0, dec0_Wg, dec0_bg, dec0_Wc, dec0_bc);
        cell_l1(h0, h1, dec1_Wg, dec1_bg, dec1_Wc, dec1_bc);
        proj_kernel<<<(NN * BB + 255) / 256, 256, 0, stream>>>(h1, projW, projb,
                                                               out + (size_t)t * BB * NN);
    }
}

// Round 2
// 13412.994 us; speedup vs baseline: 1.0617x; 1.0617x over previous
//
#include <hip/hip_runtime.h>
#include <math.h>

#define NN 512
#define BB 32
#define TT 12
#define HH 12
#define UU 64
#define MM 5
#define CAP 128
#define SMAXC (512 * 4096)   // slot stride in Xbuf (floats)

// ---------------- ELL build: one wave per row, deterministic compaction ---------
__global__ __launch_bounds__(256) void build_ell(const float* __restrict__ supports,
                                                 int* __restrict__ eidx,
                                                 float* __restrict__ eval_,
                                                 int* __restrict__ ecnt) {
    int wave = (blockIdx.x * blockDim.x + threadIdx.x) >> 6;
    int lane = threadIdx.x & 63;
    if (wave >= 2 * NN) return;
    const float* row = supports + (size_t)wave * NN;
    int base = 0;
    for (int k = 0; k < NN / 64; ++k) {
        float v = row[k * 64 + lane];
        unsigned long long m = __ballot(v != 0.0f);
        int pre = __popcll(m & ((1ull << lane) - 1ull));
        if (v != 0.0f) {
            int pos = base + pre;
            if (pos < CAP) {
                eidx[wave * CAP + pos] = k * 64 + lane;
                eval_[wave * CAP + pos] = v;
            }
        }
        base += __popcll(m);
    }
    if (lane == 0) ecnt[wave] = base < CAP ? base : CAP;
}

// ---------------- zero init ----------------------------------------------------
__global__ void zero_kernel(float* __restrict__ p, int n) {
    int i = blockIdx.x * 256 + threadIdx.x;
    if (i < n) p[i] = 0.0f;
}

// ---------------- concat builders ----------------------------------------------
// X0 slot0 of Xbuf: (N, B*C) with element [n][b*C+c]
__global__ void build_x0_l0(float* __restrict__ X0, const float* __restrict__ x, // (B,N)
                            const float* __restrict__ h,                         // (N,B,U)
                            const float* __restrict__ r) {                       // (N,B,2U) or null
    int idx = blockIdx.x * 256 + threadIdx.x;
    const int total = NN * BB * 65;
    if (idx >= total) return;
    int n = idx / (BB * 65);
    int rem = idx - n * (BB * 65);
    int b = rem / 65;
    int c = rem - b * 65;
    float v;
    if (c == 0) {
        v = x[b * NN + n];
    } else {
        int u = c - 1;
        v = h[((size_t)n * BB + b) * UU + u];
        if (r) v *= r[((size_t)n * BB + b) * (2 * UU) + u];
    }
    X0[idx] = v;
}

__global__ void build_x0_l1(float* __restrict__ X0, const float* __restrict__ h0,
                            const float* __restrict__ h1, const float* __restrict__ r) {
    int idx = blockIdx.x * 256 + threadIdx.x;
    const int total = NN * BB * 128;
    if (idx >= total) return;
    int n = idx >> 12;       // BB*128 = 4096
    int rem = idx & 4095;
    int b = rem >> 7;
    int c = rem & 127;
    float v;
    if (c < UU) {
        v = h0[((size_t)n * BB + b) * UU + c];
    } else {
        int u = c - UU;
        v = h1[((size_t)n * BB + b) * UU + u];
        if (r) v *= r[((size_t)n * BB + b) * (2 * UU) + u];
    }
    X0[idx] = v;
}

// ---------------- SpMM: row-CSR, 16-col tiles, L1-reuse oriented ----------------
// phase 0: X[1+2s] = S_s @ X[0]
// phase 1: X[2+2s] = 2 * S_s @ X[1+2s] - X[0]
// block covers 64 rows x 16 cols; thread = (row_local, fs) with a float4 of cols.
// Grid mapping: bid = fl + 8*(it + 8*(fh + FH*s)) so that blocks sharing the same
// ft (= fh*8+fl) land on the same XCD back-to-back -> shared L1/L2 lines.
__global__ __launch_bounds__(256) void spmm_csr(float* __restrict__ Xbuf,
                                                const int* __restrict__ eidx,
                                                const float* __restrict__ eval_,
                                                const int* __restrict__ ecnt,
                                                int F, int FT, int FH, int phase) {
    int bid = blockIdx.x;
    int fl = bid & 7;
    int u = bid >> 3;
    int it = u & 7;
    int v = u >> 3;
    int s = (v >= FH) ? 1 : 0;
    int fh = v - s * FH;
    int ft = fh * 8 + fl;
    if (ft >= FT) return;

    int il = threadIdx.x >> 2;          // 0..63
    int fs = threadIdx.x & 3;           // 0..3
    int row = it * 64 + il;
    int erow = s * NN + row;
    int cnt = ecnt[erow];
    int rs4 = F >> 2;                   // row stride in float4
    int f4 = ft * 4 + fs;

    const float4* X4 = (const float4*)(Xbuf + (phase ? (size_t)(1 + 2 * s) * SMAXC : 0));
    const int* ei = eidx + (size_t)erow * CAP;
    const float* ev = eval_ + (size_t)erow * CAP;

    float4 acc = make_float4(0.f, 0.f, 0.f, 0.f);
    int p = 0;
    for (; p + 4 <= cnt; p += 4) {
        int j0 = ei[p], j1 = ei[p + 1], j2 = ei[p + 2], j3 = ei[p + 3];
        float v0 = ev[p], v1 = ev[p + 1], v2 = ev[p + 2], v3 = ev[p + 3];
        float4 x0 = X4[(size_t)j0 * rs4 + f4];
        float4 x1 = X4[(size_t)j1 * rs4 + f4];
        float4 x2 = X4[(size_t)j2 * rs4 + f4];
        float4 x3 = X4[(size_t)j3 * rs4 + f4];
        acc.x += v0 * x0.x + v1 * x1.x + v2 * x2.x + v3 * x3.x;
        acc.y += v0 * x0.y + v1 * x1.y + v2 * x2.y + v3 * x3.y;
        acc.z += v0 * x0.z + v1 * x1.z + v2 * x2.z + v3 * x3.z;
        acc.w += v0 * x0.w + v1 * x1.w + v2 * x2.w + v3 * x3.w;
    }
    for (; p < cnt; ++p) {
        int j = ei[p]; float vv = ev[p];
        float4 xx = X4[(size_t)j * rs4 + f4];
        acc.x += vv * xx.x; acc.y += vv * xx.y; acc.z += vv * xx.z; acc.w += vv * xx.w;
    }

    float4 res;
    if (phase) {
        const float4* X0v = (const float4*)Xbuf;
        float4 xpp = X0v[(size_t)row * rs4 + f4];
        res.x = 2.f * acc.x - xpp.x; res.y = 2.f * acc.y - xpp.y;
        res.z = 2.f * acc.z - xpp.z; res.w = 2.f * acc.w - xpp.w;
    } else {
        res = acc;
    }
    float4* Y = (float4*)(Xbuf + (size_t)(phase ? (2 + 2 * s) : (1 + 2 * s)) * SMAXC);
    Y[(size_t)row * rs4 + f4] = res;
}

// ---------------- weight GEMM v2 + bias + activation ----------------------------
// out[r=(n*B+b)][o] = act( sum_{k'=m*C+c} Xbuf[m][n][b*C+c] * W[c*5+m][o] + bias[o] )
// TM rows x 64 cols per block; 256 threads (16x16); thread: TR rows x 4 cols.
template<int TM, bool L0>
__global__ __launch_bounds__(256) void wgemm2(const float* __restrict__ Xbuf,
                                              const float* __restrict__ W,
                                              const float* __restrict__ bias,
                                              float* __restrict__ out,
                                              int Ototal, int act) {
    constexpr int C  = L0 ? 65 : 128;
    constexpr int Kp = 5 * C;
    constexpr int KT = (Kp + 31) / 32;
    constexpr int F  = BB * C;          // Xbuf row stride (floats)
    constexpr int TR = TM / 16;

    __shared__ float  At[TM][33];
    __shared__ float4 Ws[32][16];       // 32 k x 64 cols

    int r0 = blockIdx.x * TM;
    int o0 = blockIdx.y * 64;
    int tid = threadIdx.x;
    int tx = tid & 15, ty = tid >> 4;

    float acc[TR][4];
    #pragma unroll
    for (int i = 0; i < TR; ++i)
        for (int j = 0; j < 4; ++j) acc[i][j] = 0.f;

    for (int kt = 0; kt < KT; ++kt) {
        // stage A tile (gathered, zero-padded tail)
        #pragma unroll
        for (int i = 0; i < TM * 32 / 256; ++i) {
            int p = i * 256 + tid;
            int rr = p >> 5, kk = p & 31;
            int k = kt * 32 + kk;
            float v = 0.f;
            if (k < Kp) {
                int m, c;
                if (L0) { m = (k * 1009) >> 16; c = k - m * 65; }
                else    { m = k >> 7;           c = k & 127;    }
                int r = r0 + rr;
                int n = r >> 5, b = r & 31;
                v = Xbuf[(size_t)m * SMAXC + (size_t)n * F + b * C + c];
            }
            At[rr][kk] = v;
        }
        // stage W tile (row permutation c*5+m, contiguous in o)
        #pragma unroll
        for (int i = 0; i < 2; ++i) {
            int p = i * 256 + tid;
            int kk = p >> 4, o4 = p & 15;
            int k = kt * 32 + kk;
            float4 vv = make_float4(0.f, 0.f, 0.f, 0.f);
            if (k < Kp) {
                int m, c;
                if (L0) { m = (k * 1009) >> 16; c = k - m * 65; }
                else    { m = k >> 7;           c = k & 127;    }
                vv = *(const float4*)&W[(size_t)(c * 5 + m) * Ototal + o0 + o4 * 4];
            }
            Ws[kk][o4] = vv;
        }
        __syncthreads();
        #pragma unroll 8
        for (int kk = 0; kk < 32; ++kk) {
            float4 w = Ws[kk][tx];
            float a[TR];
            #pragma unroll
            for (int i = 0; i < TR; ++i) a[i] = At[ty * TR + i][kk];
            #pragma unroll
            for (int i = 0; i < TR; ++i) {
                acc[i][0] += a[i] * w.x;
                acc[i][1] += a[i] * w.y;
                acc[i][2] += a[i] * w.z;
                acc[i][3] += a[i] * w.w;
            }
        }
        __syncthreads();
    }

    int o = o0 + tx * 4;
    float4 bs = *(const float4*)&bias[o];
    #pragma unroll
    for (int i = 0; i < TR; ++i) {
        int r = r0 + ty * TR + i;
        float4 res;
        res.x = acc[i][0] + bs.x;
        res.y = acc[i][1] + bs.y;
        res.z = acc[i][2] + bs.z;
        res.w = acc[i][3] + bs.w;
        if (act == 0) {
            res.x = 1.f / (1.f + expf(-res.x));
            res.y = 1.f / (1.f + expf(-res.y));
            res.z = 1.f / (1.f + expf(-res.z));
            res.w = 1.f / (1.f + expf(-res.w));
        } else {
            res.x = tanhf(res.x);
            res.y = tanhf(res.y);
            res.z = tanhf(res.z);
            res.w = tanhf(res.w);
        }
        *(float4*)&out[(size_t)r * Ototal + o] = res;
    }
}

// ---------------- GRU state update ----------------------------------------------
__global__ void gru_update(float* __restrict__ h, const float* __restrict__ g,
                           const float* __restrict__ c) {
    int idx = blockIdx.x * 256 + threadIdx.x;
    if (idx >= NN * BB * UU) return;
    int nb = idx >> 6;
    int u = idx & 63;
    float ug = g[(size_t)nb * (2 * UU) + UU + u];
    float hv = h[idx];
    h[idx] = ug * hv + (1.0f - ug) * c[idx];
}

// ---------------- projection ----------------------------------------------------
__global__ void proj_kernel(const float* __restrict__ h1, const float* __restrict__ pW,
                            const float* __restrict__ pb, float* __restrict__ outt) {
    int idx = blockIdx.x * 256 + threadIdx.x;   // B*N threads
    if (idx >= NN * BB) return;
    int b = idx >> 9;
    int n = idx & 511;
    const float* hp = h1 + ((size_t)n * BB + b) * UU;
    float acc = pb[0];
    #pragma unroll 8
    for (int u = 0; u < UU; ++u) acc += hp[u] * pW[u];
    outt[b * NN + n] = acc;
}

// ================================================================================
extern "C" void kernel_launch(void* const* d_in, const int* in_sizes, int n_in,
                              void* d_out, int out_size, void* d_ws, size_t ws_size,
                              hipStream_t stream) {
    const float* inputs   = (const float*)d_in[0];
    const float* supports = (const float*)d_in[1];
    const float* enc0_Wg = (const float*)d_in[2];
    const float* enc0_bg = (const float*)d_in[3];
    const float* enc0_Wc = (const float*)d_in[4];
    const float* enc0_bc = (const float*)d_in[5];
    const float* enc1_Wg = (const float*)d_in[6];
    const float* enc1_bg = (const float*)d_in[7];
    const float* enc1_Wc = (const float*)d_in[8];
    const float* enc1_bc = (const float*)d_in[9];
    const float* dec0_Wg = (const float*)d_in[10];
    const float* dec0_bg = (const float*)d_in[11];
    const float* dec0_Wc = (const float*)d_in[12];
    const float* dec0_bc = (const float*)d_in[13];
    const float* dec1_Wg = (const float*)d_in[14];
    const float* dec1_bg = (const float*)d_in[15];
    const float* dec1_Wc = (const float*)d_in[16];
    const float* dec1_bc = (const float*)d_in[17];
    const float* projW   = (const float*)d_in[18];
    const float* projb   = (const float*)d_in[19];
    float* out = (float*)d_out;

    char* wsb = (char*)d_ws;
    size_t off = 0;
    auto alloc = [&](size_t bytes) -> char* {
        char* p = wsb + off;
        off = (off + bytes + 255) & ~(size_t)255;
        return p;
    };
    int*   eidx  = (int*)alloc((size_t)2 * NN * CAP * 4);
    float* eval_ = (float*)alloc((size_t)2 * NN * CAP * 4);
    int*   ecnt  = (int*)alloc((size_t)2 * NN * 4);
    float* h0    = (float*)alloc((size_t)NN * BB * UU * 4);
    float* h1    = (float*)alloc((size_t)NN * BB * UU * 4);
    float* xzero = (float*)alloc((size_t)NN * BB * 4);
    float* g     = (float*)alloc((size_t)NN * BB * 2 * UU * 4);
    float* cb    = (float*)alloc((size_t)NN * BB * UU * 4);
    float* Xbuf  = (float*)alloc((size_t)5 * SMAXC * 4);
    if (off > ws_size) return;

    // preprocessing
    build_ell<<<256, 256, 0, stream>>>(supports, eidx, eval_, ecnt);
    {
        int nz = NN * BB * UU * 2 + NN * BB;  // h0, h1, xzero are contiguous
        zero_kernel<<<(nz + 255) / 256, 256, 0, stream>>>(h0, nz);
    }

    auto diffusion = [&](int F) {
        int FT = F / 16;
        int FH = (FT + 7) / 8;
        dim3 gr(8 * 8 * FH * 2);
        spmm_csr<<<gr, 256, 0, stream>>>(Xbuf, eidx, eval_, ecnt, F, FT, FH, 0);
        spmm_csr<<<gr, 256, 0, stream>>>(Xbuf, eidx, eval_, ecnt, F, FT, FH, 1);
    };

    auto cell_l0 = [&](const float* x_bn, float* h, const float* Wgp, const float* bgp,
                       const float* Wcp, const float* bcp) {
        const int tot = NN * BB * 65;
        build_x0_l0<<<(tot + 255) / 256, 256, 0, stream>>>(Xbuf, x_bn, h, nullptr);
        diffusion(BB * 65);
        wgemm2<64, true><<<dim3(NN * BB / 64, 2), 256, 0, stream>>>(Xbuf, Wgp, bgp, g, 128, 0);
        build_x0_l0<<<(tot + 255) / 256, 256, 0, stream>>>(Xbuf, x_bn, h, g);
        diffusion(BB * 65);
        wgemm2<32, true><<<dim3(NN * BB / 32, 1), 256, 0, stream>>>(Xbuf, Wcp, bcp, cb, 64, 1);
        gru_update<<<NN * BB * UU / 256, 256, 0, stream>>>(h, g, cb);
    };
    auto cell_l1 = [&](const float* hin, float* h, const float* Wgp, const float* bgp,
                       const float* Wcp, const float* bcp) {
        const int tot = NN * BB * 128;
        build_x0_l1<<<(tot + 255) / 256, 256, 0, stream>>>(Xbuf, hin, h, nullptr);
        diffusion(BB * 128);
        wgemm2<64, false><<<dim3(NN * BB / 64, 2), 256, 0, stream>>>(Xbuf, Wgp, bgp, g, 128, 0);
        build_x0_l1<<<(tot + 255) / 256, 256, 0, stream>>>(Xbuf, hin, h, g);
        diffusion(BB * 128);
        wgemm2<32, false><<<dim3(NN * BB / 32, 1), 256, 0, stream>>>(Xbuf, Wcp, bcp, cb, 64, 1);
        gru_update<<<NN * BB * UU / 256, 256, 0, stream>>>(h, g, cb);
    };

    // encoder
    for (int t = 0; t < TT; ++t) {
        cell_l0(inputs + (size_t)t * BB * NN, h0, enc0_Wg, enc0_bg, enc0_Wc, enc0_bc);
        cell_l1(h0, h1, enc1_Wg, enc1_bg, enc1_Wc, enc1_bc);
    }
    // decoder
    for (int t = 0; t < HH; ++t) {
        const float* xin = (t == 0) ? xzero : (out + (size_t)(t - 1) * BB * NN);
        cell_l0(xin, h0, dec0_Wg, dec0_bg, dec0_Wc, dec0_bc);
        cell_l1(h0, h1, dec1_Wg, dec1_bg, dec1_Wc, dec1_bc);
        proj_kernel<<<(NN * BB + 255) / 256, 256, 0, stream>>>(h1, projW, projb,
                                                               out + (size_t)t * BB * NN);
    }
}

// Round 3
// 11508.921 us; speedup vs baseline: 1.2373x; 1.1654x over previous
//
#include <hip/hip_runtime.h>
#include <math.h>

#define NN 512
#define BB 32
#define TT 12
#define HH 12
#define UU 64
#define CAP 128
#define SMAXC (512 * 4096)   // slot stride in Xbuf (floats)

// ---------------- ELL build (transposed layout): one wave per row ---------------
// eidxT[p*1024 + wave], evalT[p*1024 + wave]; wave = s*512 + row
__global__ __launch_bounds__(256) void build_ell(const float* __restrict__ supports,
                                                 int* __restrict__ eidxT,
                                                 float* __restrict__ evalT,
                                                 int* __restrict__ ecnt) {
    int wave = (blockIdx.x * blockDim.x + threadIdx.x) >> 6;
    int lane = threadIdx.x & 63;
    if (wave >= 2 * NN) return;
    const float* row = supports + (size_t)wave * NN;
    int base = 0;
    for (int k = 0; k < NN / 64; ++k) {
        float v = row[k * 64 + lane];
        unsigned long long m = __ballot(v != 0.0f);
        int pre = __popcll(m & ((1ull << lane) - 1ull));
        if (v != 0.0f) {
            int pos = base + pre;
            if (pos < CAP) {
                eidxT[(size_t)pos * 1024 + wave] = k * 64 + lane;
                evalT[(size_t)pos * 1024 + wave] = v;
            }
        }
        base += __popcll(m);
    }
    if (lane == 0) ecnt[wave] = base < CAP ? base : CAP;
}

// ---------------- zero init ----------------------------------------------------
__global__ void zero_kernel(float* __restrict__ p, int n) {
    int i = blockIdx.x * 256 + threadIdx.x;
    if (i < n) p[i] = 0.0f;
}

// ---------------- fused diffusion ----------------------------------------------
// Per block: 8 columns (f = ft*16 + gh*8 .. +7) of the (B*C)-wide X matrix.
// Stages X0 tile in LDS (built on the fly from x/h/r), computes X1 = S@X0 and
// X2 = 2 S@X1 - X0 for both supports, writes slots 0..4 of Xbuf.
template<bool L0>
__global__ __launch_bounds__(512) void diffuse(const float* __restrict__ xsrc,
                                               const float* __restrict__ hst,
                                               const float* __restrict__ rg,
                                               float* __restrict__ Xbuf,
                                               const int* __restrict__ eidxT,
                                               const float* __restrict__ evalT,
                                               const int* __restrict__ ecnt) {
    constexpr int C = L0 ? 65 : 128;
    constexpr int F = BB * C;
    __shared__ float T0[512 * 8];
    __shared__ float T1[512 * 8];
    int ft = blockIdx.x;
    int gh = blockIdx.y;
    int tid = threadIdx.x;
    int fbase = ft * 16 + gh * 8;

    // ---- stage X0 tile (swizzled: addr = n*8 + ((gl^n)&1)*4 + e) ----
    #pragma unroll
    for (int i = 0; i < 8; ++i) {
        int t = i * 512 + tid;
        int n = t >> 3, fi = t & 7;
        int f = fbase + fi;
        int b, c;
        if (L0) { b = (f * 64528) >> 22; c = f - b * 65; }
        else    { b = f >> 7;            c = f & 127;    }
        float v;
        if (L0) {
            if (c == 0) v = xsrc[b * NN + n];
            else {
                int u = c - 1;
                v = hst[((size_t)n * BB + b) * UU + u];
                if (rg) v *= rg[((size_t)n * BB + b) * (2 * UU) + u];
            }
        } else {
            if (c < UU) v = xsrc[((size_t)n * BB + b) * UU + c];
            else {
                int u = c - UU;
                v = hst[((size_t)n * BB + b) * UU + u];
                if (rg) v *= rg[((size_t)n * BB + b) * (2 * UU) + u];
            }
        }
        T0[n * 8 + ((( fi >> 2) ^ n) & 1) * 4 + (fi & 3)] = v;
    }
    __syncthreads();

    int row = tid;  // 512 threads, one row each
    // ---- write X0 slot ----
    {
        float4 v0 = *(float4*)&T0[row * 8 + (row & 1) * 4];
        float4 v1 = *(float4*)&T0[row * 8 + ((row & 1) ^ 1) * 4];
        float4* dst = (float4*)&Xbuf[(size_t)row * F + fbase];
        dst[0] = v0; dst[1] = v1;
    }

    for (int s = 0; s < 2; ++s) {
        int erow = s * NN + row;
        int cnt = ecnt[erow];
        const int*   ei = eidxT + erow;
        const float* ev = evalT + erow;
        // ---- hop 1: X1 = S @ X0 ----
        float4 a0 = make_float4(0.f, 0.f, 0.f, 0.f);
        float4 a1 = make_float4(0.f, 0.f, 0.f, 0.f);
        for (int p = 0; p < cnt; ++p) {
            int j   = ei[(size_t)p * 1024];
            float v = ev[(size_t)p * 1024];
            float4 x0 = *(float4*)&T0[j * 8 + (j & 1) * 4];
            float4 x1 = *(float4*)&T0[j * 8 + ((j & 1) ^ 1) * 4];
            a0.x += v * x0.x; a0.y += v * x0.y; a0.z += v * x0.z; a0.w += v * x0.w;
            a1.x += v * x1.x; a1.y += v * x1.y; a1.z += v * x1.z; a1.w += v * x1.w;
        }
        {
            float4* dst = (float4*)&Xbuf[(size_t)(1 + 2 * s) * SMAXC + (size_t)row * F + fbase];
            dst[0] = a0; dst[1] = a1;
            *(float4*)&T1[row * 8 + (row & 1) * 4]       = a0;
            *(float4*)&T1[row * 8 + ((row & 1) ^ 1) * 4] = a1;
        }
        __syncthreads();
        // ---- hop 2: X2 = 2 S @ X1 - X0 ----
        float4 b0 = make_float4(0.f, 0.f, 0.f, 0.f);
        float4 b1 = make_float4(0.f, 0.f, 0.f, 0.f);
        for (int p = 0; p < cnt; ++p) {
            int j   = ei[(size_t)p * 1024];
            float v = ev[(size_t)p * 1024];
            float4 x0 = *(float4*)&T1[j * 8 + (j & 1) * 4];
            float4 x1 = *(float4*)&T1[j * 8 + ((j & 1) ^ 1) * 4];
            b0.x += v * x0.x; b0.y += v * x0.y; b0.z += v * x0.z; b0.w += v * x0.w;
            b1.x += v * x1.x; b1.y += v * x1.y; b1.z += v * x1.z; b1.w += v * x1.w;
        }
        {
            float4 p0 = *(float4*)&T0[row * 8 + (row & 1) * 4];
            float4 p1 = *(float4*)&T0[row * 8 + ((row & 1) ^ 1) * 4];
            float4 r0, r1;
            r0.x = 2.f * b0.x - p0.x; r0.y = 2.f * b0.y - p0.y;
            r0.z = 2.f * b0.z - p0.z; r0.w = 2.f * b0.w - p0.w;
            r1.x = 2.f * b1.x - p1.x; r1.y = 2.f * b1.y - p1.y;
            r1.z = 2.f * b1.z - p1.z; r1.w = 2.f * b1.w - p1.w;
            float4* dst = (float4*)&Xbuf[(size_t)(2 + 2 * s) * SMAXC + (size_t)row * F + fbase];
            dst[0] = r0; dst[1] = r1;
        }
        __syncthreads();
    }
}

// ---------------- gate GEMM: 64 rows x 128 cols, sigmoid ------------------------
// out[r][o] = sigmoid( sum_{k=m*C+c} Xbuf[m][n][b*C+c] * W[c*5+m][o] + bias[o] )
template<bool L0>
__global__ __launch_bounds__(256) void wgemm_gate(const float* __restrict__ Xbuf,
                                                  const float* __restrict__ W,
                                                  const float* __restrict__ bias,
                                                  float* __restrict__ out) {
    constexpr int C  = L0 ? 65 : 128;
    constexpr int Kp = 5 * C;
    constexpr int KT = (Kp + 31) / 32;
    constexpr int F  = BB * C;
    constexpr int O  = 2 * UU;  // 128

    __shared__ float  At[64][33];
    __shared__ float4 Ws[32][32];

    int r0 = blockIdx.x * 64;
    int tid = threadIdx.x;
    int tx = tid & 15, ty = tid >> 4;

    float acc[4][8];
    #pragma unroll
    for (int i = 0; i < 4; ++i)
        #pragma unroll
        for (int j = 0; j < 8; ++j) acc[i][j] = 0.f;

    for (int kt = 0; kt < KT; ++kt) {
        #pragma unroll
        for (int i = 0; i < 8; ++i) {
            int p = i * 256 + tid;
            int rr = p >> 5, kk = p & 31;
            int k = kt * 32 + kk;
            float v = 0.f;
            if (k < Kp) {
                int m, c;
                if (L0) { m = (k * 64528) >> 22; c = k - m * 65; }
                else    { m = k >> 7;            c = k & 127;    }
                int r = r0 + rr;
                int n = r >> 5, b = r & 31;
                v = Xbuf[(size_t)m * SMAXC + (size_t)n * F + b * C + c];
            }
            At[rr][kk] = v;
        }
        #pragma unroll
        for (int i = 0; i < 4; ++i) {
            int p = i * 256 + tid;
            int kk = p >> 5, o4 = p & 31;
            int k = kt * 32 + kk;
            float4 vv = make_float4(0.f, 0.f, 0.f, 0.f);
            if (k < Kp) {
                int m, c;
                if (L0) { m = (k * 64528) >> 22; c = k - m * 65; }
                else    { m = k >> 7;            c = k & 127;    }
                vv = *(const float4*)&W[(size_t)(c * 5 + m) * O + o4 * 4];
            }
            Ws[kk][(o4 & 1) * 16 + (o4 >> 1)] = vv;  // split-half permutation
        }
        __syncthreads();
        #pragma unroll 4
        for (int kk = 0; kk < 32; ++kk) {
            float4 w0 = Ws[kk][tx];
            float4 w1 = Ws[kk][tx + 16];
            float a[4];
            #pragma unroll
            for (int i = 0; i < 4; ++i) a[i] = At[ty * 4 + i][kk];
            #pragma unroll
            for (int i = 0; i < 4; ++i) {
                acc[i][0] += a[i] * w0.x; acc[i][1] += a[i] * w0.y;
                acc[i][2] += a[i] * w0.z; acc[i][3] += a[i] * w0.w;
                acc[i][4] += a[i] * w1.x; acc[i][5] += a[i] * w1.y;
                acc[i][6] += a[i] * w1.z; acc[i][7] += a[i] * w1.w;
            }
        }
        __syncthreads();
    }

    int o = tx * 8;
    float4 bs0 = *(const float4*)&bias[o];
    float4 bs1 = *(const float4*)&bias[o + 4];
    #pragma unroll
    for (int i = 0; i < 4; ++i) {
        int r = r0 + ty * 4 + i;
        float4 v0, v1;
        v0.x = acc[i][0] + bs0.x; v0.y = acc[i][1] + bs0.y;
        v0.z = acc[i][2] + bs0.z; v0.w = acc[i][3] + bs0.w;
        v1.x = acc[i][4] + bs1.x; v1.y = acc[i][5] + bs1.y;
        v1.z = acc[i][6] + bs1.z; v1.w = acc[i][7] + bs1.w;
        v0.x = 1.f / (1.f + expf(-v0.x)); v0.y = 1.f / (1.f + expf(-v0.y));
        v0.z = 1.f / (1.f + expf(-v0.z)); v0.w = 1.f / (1.f + expf(-v0.w));
        v1.x = 1.f / (1.f + expf(-v1.x)); v1.y = 1.f / (1.f + expf(-v1.y));
        v1.z = 1.f / (1.f + expf(-v1.z)); v1.w = 1.f / (1.f + expf(-v1.w));
        *(float4*)&out[(size_t)r * O + o]     = v0;
        *(float4*)&out[(size_t)r * O + o + 4] = v1;
    }
}

// ---------------- candidate GEMM + tanh + fused GRU update ----------------------
// c = tanh(A@Wc + bc); h = u*h + (1-u)*c, u = g[:,64:128]
template<bool L0>
__global__ __launch_bounds__(256) void wgemm_cand(const float* __restrict__ Xbuf,
                                                  const float* __restrict__ W,
                                                  const float* __restrict__ bias,
                                                  const float* __restrict__ g,
                                                  float* __restrict__ h) {
    constexpr int C  = L0 ? 65 : 128;
    constexpr int Kp = 5 * C;
    constexpr int KT = (Kp + 31) / 32;
    constexpr int F  = BB * C;
    constexpr int O  = UU;  // 64

    __shared__ float  At[64][33];
    __shared__ float4 Ws[32][16];

    int r0 = blockIdx.x * 64;
    int tid = threadIdx.x;
    int tx = tid & 15, ty = tid >> 4;

    float acc[4][4];
    #pragma unroll
    for (int i = 0; i < 4; ++i)
        #pragma unroll
        for (int j = 0; j < 4; ++j) acc[i][j] = 0.f;

    for (int kt = 0; kt < KT; ++kt) {
        #pragma unroll
        for (int i = 0; i < 8; ++i) {
            int p = i * 256 + tid;
            int rr = p >> 5, kk = p & 31;
            int k = kt * 32 + kk;
            float v = 0.f;
            if (k < Kp) {
                int m, c;
                if (L0) { m = (k * 64528) >> 22; c = k - m * 65; }
                else    { m = k >> 7;            c = k & 127;    }
                int r = r0 + rr;
                int n = r >> 5, b = r & 31;
                v = Xbuf[(size_t)m * SMAXC + (size_t)n * F + b * C + c];
            }
            At[rr][kk] = v;
        }
        #pragma unroll
        for (int i = 0; i < 2; ++i) {
            int p = i * 256 + tid;
            int kk = p >> 4, o4 = p & 15;
            int k = kt * 32 + kk;
            float4 vv = make_float4(0.f, 0.f, 0.f, 0.f);
            if (k < Kp) {
                int m, c;
                if (L0) { m = (k * 64528) >> 22; c = k - m * 65; }
                else    { m = k >> 7;            c = k & 127;    }
                vv = *(const float4*)&W[(size_t)(c * 5 + m) * O + o4 * 4];
            }
            Ws[kk][o4] = vv;
        }
        __syncthreads();
        #pragma unroll 4
        for (int kk = 0; kk < 32; ++kk) {
            float4 w = Ws[kk][tx];
            float a[4];
            #pragma unroll
            for (int i = 0; i < 4; ++i) a[i] = At[ty * 4 + i][kk];
            #pragma unroll
            for (int i = 0; i < 4; ++i) {
                acc[i][0] += a[i] * w.x; acc[i][1] += a[i] * w.y;
                acc[i][2] += a[i] * w.z; acc[i][3] += a[i] * w.w;
            }
        }
        __syncthreads();
    }

    int o = tx * 4;
    float4 bs = *(const float4*)&bias[o];
    #pragma unroll
    for (int i = 0; i < 4; ++i) {
        int r = r0 + ty * 4 + i;
        float4 cv;
        cv.x = tanhf(acc[i][0] + bs.x);
        cv.y = tanhf(acc[i][1] + bs.y);
        cv.z = tanhf(acc[i][2] + bs.z);
        cv.w = tanhf(acc[i][3] + bs.w);
        float4 u  = *(const float4*)&g[(size_t)r * (2 * UU) + UU + o];
        float4* hp = (float4*)&h[(size_t)r * UU + o];
        float4 hv = *hp;
        hv.x = u.x * hv.x + (1.f - u.x) * cv.x;
        hv.y = u.y * hv.y + (1.f - u.y) * cv.y;
        hv.z = u.z * hv.z + (1.f - u.z) * cv.z;
        hv.w = u.w * hv.w + (1.f - u.w) * cv.w;
        *hp = hv;
    }
}

// ---------------- projection ----------------------------------------------------
__global__ void proj_kernel(const float* __restrict__ h1, const float* __restrict__ pW,
                            const float* __restrict__ pb, float* __restrict__ outt) {
    int r = blockIdx.x * 256 + threadIdx.x;  // r = n*32+b
    if (r >= NN * BB) return;
    int n = r >> 5, b = r & 31;
    const float4* hp = (const float4*)&h1[(size_t)r * UU];
    float acc = pb[0];
    #pragma unroll
    for (int u4 = 0; u4 < 16; ++u4) {
        float4 hv = hp[u4];
        float4 wv = *(const float4*)&pW[u4 * 4];
        acc += hv.x * wv.x + hv.y * wv.y + hv.z * wv.z + hv.w * wv.w;
    }
    outt[b * NN + n] = acc;
}

// ================================================================================
extern "C" void kernel_launch(void* const* d_in, const int* in_sizes, int n_in,
                              void* d_out, int out_size, void* d_ws, size_t ws_size,
                              hipStream_t stream) {
    const float* inputs   = (const float*)d_in[0];
    const float* supports = (const float*)d_in[1];
    const float* enc0_Wg = (const float*)d_in[2];
    const float* enc0_bg = (const float*)d_in[3];
    const float* enc0_Wc = (const float*)d_in[4];
    const float* enc0_bc = (const float*)d_in[5];
    const float* enc1_Wg = (const float*)d_in[6];
    const float* enc1_bg = (const float*)d_in[7];
    const float* enc1_Wc = (const float*)d_in[8];
    const float* enc1_bc = (const float*)d_in[9];
    const float* dec0_Wg = (const float*)d_in[10];
    const float* dec0_bg = (const float*)d_in[11];
    const float* dec0_Wc = (const float*)d_in[12];
    const float* dec0_bc = (const float*)d_in[13];
    const float* dec1_Wg = (const float*)d_in[14];
    const float* dec1_bg = (const float*)d_in[15];
    const float* dec1_Wc = (const float*)d_in[16];
    const float* dec1_bc = (const float*)d_in[17];
    const float* projW   = (const float*)d_in[18];
    const float* projb   = (const float*)d_in[19];
    float* out = (float*)d_out;

    char* wsb = (char*)d_ws;
    size_t off = 0;
    auto alloc = [&](size_t bytes) -> char* {
        char* p = wsb + off;
        off = (off + bytes + 255) & ~(size_t)255;
        return p;
    };
    int*   eidxT = (int*)alloc((size_t)CAP * 1024 * 4);
    float* evalT = (float*)alloc((size_t)CAP * 1024 * 4);
    int*   ecnt  = (int*)alloc((size_t)2 * NN * 4);
    float* h0    = (float*)alloc((size_t)NN * BB * UU * 4);
    float* h1    = (float*)alloc((size_t)NN * BB * UU * 4);
    float* xzero = (float*)alloc((size_t)NN * BB * 4);
    float* g     = (float*)alloc((size_t)NN * BB * 2 * UU * 4);
    float* Xbuf  = (float*)alloc((size_t)5 * SMAXC * 4);
    if (off > ws_size) return;

    build_ell<<<256, 256, 0, stream>>>(supports, eidxT, evalT, ecnt);
    {
        int nz = NN * BB * UU * 2 + NN * BB;  // h0, h1, xzero contiguous
        zero_kernel<<<(nz + 255) / 256, 256, 0, stream>>>(h0, nz);
    }

    auto cell_l0 = [&](const float* x_bn, float* h, const float* Wgp, const float* bgp,
                       const float* Wcp, const float* bcp) {
        dim3 dg(130, 2);
        diffuse<true><<<dg, 512, 0, stream>>>(x_bn, h, nullptr, Xbuf, eidxT, evalT, ecnt);
        wgemm_gate<true><<<NN * BB / 64, 256, 0, stream>>>(Xbuf, Wgp, bgp, g);
        diffuse<true><<<dg, 512, 0, stream>>>(x_bn, h, g, Xbuf, eidxT, evalT, ecnt);
        wgemm_cand<true><<<NN * BB / 64, 256, 0, stream>>>(Xbuf, Wcp, bcp, g, h);
    };
    auto cell_l1 = [&](const float* hin, float* h, const float* Wgp, const float* bgp,
                       const float* Wcp, const float* bcp) {
        dim3 dg(256, 2);
        diffuse<false><<<dg, 512, 0, stream>>>(hin, h, nullptr, Xbuf, eidxT, evalT, ecnt);
        wgemm_gate<false><<<NN * BB / 64, 256, 0, stream>>>(Xbuf, Wgp, bgp, g);
        diffuse<false><<<dg, 512, 0, stream>>>(hin, h, g, Xbuf, eidxT, evalT, ecnt);
        wgemm_cand<false><<<NN * BB / 64, 256, 0, stream>>>(Xbuf, Wcp, bcp, g, h);
    };

    for (int t = 0; t < TT; ++t) {
        cell_l0(inputs + (size_t)t * BB * NN, h0, enc0_Wg, enc0_bg, enc0_Wc, enc0_bc);
        cell_l1(h0, h1, enc1_Wg, enc1_bg, enc1_Wc, enc1_bc);
    }
    for (int t = 0; t < HH; ++t) {
        const float* xin = (t == 0) ? xzero : (out + (size_t)(t - 1) * BB * NN);
        cell_l0(xin, h0, dec0_Wg, dec0_bg, dec0_Wc, dec0_bc);
        cell_l1(h0, h1, dec1_Wg, dec1_bg, dec1_Wc, dec1_bc);
        proj_kernel<<<(NN * BB + 255) / 256, 256, 0, stream>>>(h1, projW, projb,
                                                               out + (size_t)t * BB * NN);
    }
}

// Round 4
// 7833.897 us; speedup vs baseline: 1.8177x; 1.4691x over previous
//
#include <hip/hip_runtime.h>
#include <math.h>

#define NN 512
#define BB 32
#define TT 12
#define HH 12
#define UU 64
#define CAP 128
#define RTOT (NN * BB)          // 16384 rows
#define SMAXC (512 * 4096)      // slot stride in Xbuf (floats)

__device__ __forceinline__ float sigm(float x) { return 1.f / (1.f + expf(-x)); }

// ---------------- ELL build (transposed layout): one wave per row ---------------
__global__ __launch_bounds__(256) void build_ell(const float* __restrict__ supports,
                                                 int* __restrict__ eidxT,
                                                 float* __restrict__ evalT,
                                                 int* __restrict__ ecnt) {
    int wave = (blockIdx.x * blockDim.x + threadIdx.x) >> 6;
    int lane = threadIdx.x & 63;
    if (wave >= 2 * NN) return;
    const float* row = supports + (size_t)wave * NN;
    int base = 0;
    for (int k = 0; k < NN / 64; ++k) {
        float v = row[k * 64 + lane];
        unsigned long long m = __ballot(v != 0.0f);
        int pre = __popcll(m & ((1ull << lane) - 1ull));
        if (v != 0.0f) {
            int pos = base + pre;
            if (pos < CAP) {
                eidxT[(size_t)pos * 1024 + wave] = k * 64 + lane;
                evalT[(size_t)pos * 1024 + wave] = v;
            }
        }
        base += __popcll(m);
    }
    if (lane == 0) ecnt[wave] = base < CAP ? base : CAP;
}

__global__ void zero_kernel(float* __restrict__ p, int n) {
    int i = blockIdx.x * 256 + threadIdx.x;
    if (i < n) p[i] = 0.0f;
}

// ---------------- fused diffusion (one support per block via blockIdx.z) --------
// If pg != null, the h-part is gated: h * sigmoid(pg0 + pg1 + bg)  (r-gate fusion)
template<bool L0>
__global__ __launch_bounds__(512) void diffuse(const float* __restrict__ xsrc,
                                               const float* __restrict__ hst,
                                               const float* __restrict__ pg,
                                               const float* __restrict__ bg,
                                               float* __restrict__ Xbuf,
                                               const int* __restrict__ eidxT,
                                               const float* __restrict__ evalT,
                                               const int* __restrict__ ecnt) {
    constexpr int C = L0 ? 65 : 128;
    constexpr int F = BB * C;
    __shared__ float T0[512 * 8];
    __shared__ float T1[512 * 8];
    int fbase = blockIdx.x * 16 + blockIdx.y * 8;
    int s = blockIdx.z;
    int tid = threadIdx.x;

    #pragma unroll
    for (int i = 0; i < 8; ++i) {
        int t = i * 512 + tid;
        int n = t >> 3, fi = t & 7;
        int f = fbase + fi;
        int b, c;
        if (L0) { b = (f * 64528) >> 22; c = f - b * 65; }
        else    { b = f >> 7;            c = f & 127;    }
        float v;
        if (L0) {
            if (c == 0) v = xsrc[b * NN + n];
            else {
                int u = c - 1;
                int r = n * BB + b;
                v = hst[(size_t)r * UU + u];
                if (pg) v *= sigm(pg[(size_t)r * 128 + u] +
                                  pg[(size_t)(RTOT + r) * 128 + u] + bg[u]);
            }
        } else {
            int r = n * BB + b;
            if (c < UU) v = xsrc[(size_t)r * UU + c];
            else {
                int u = c - UU;
                v = hst[(size_t)r * UU + u];
                if (pg) v *= sigm(pg[(size_t)r * 128 + u] +
                                  pg[(size_t)(RTOT + r) * 128 + u] + bg[u]);
            }
        }
        T0[n * 8 + (((fi >> 2) ^ n) & 1) * 4 + (fi & 3)] = v;
    }
    __syncthreads();

    int row = tid;
    if (s == 0) {
        float4 v0 = *(float4*)&T0[row * 8 + (row & 1) * 4];
        float4 v1 = *(float4*)&T0[row * 8 + ((row & 1) ^ 1) * 4];
        float4* dst = (float4*)&Xbuf[(size_t)row * F + fbase];
        dst[0] = v0; dst[1] = v1;
    }

    int erow = s * NN + row;
    int cnt = ecnt[erow];
    const int*   ei = eidxT + erow;
    const float* ev = evalT + erow;

    // hop 1: X1 = S @ X0
    float4 a0 = make_float4(0.f, 0.f, 0.f, 0.f);
    float4 a1 = make_float4(0.f, 0.f, 0.f, 0.f);
    for (int p = 0; p < cnt; ++p) {
        int j   = ei[(size_t)p * 1024];
        float v = ev[(size_t)p * 1024];
        float4 x0 = *(float4*)&T0[j * 8 + (j & 1) * 4];
        float4 x1 = *(float4*)&T0[j * 8 + ((j & 1) ^ 1) * 4];
        a0.x += v * x0.x; a0.y += v * x0.y; a0.z += v * x0.z; a0.w += v * x0.w;
        a1.x += v * x1.x; a1.y += v * x1.y; a1.z += v * x1.z; a1.w += v * x1.w;
    }
    {
        float4* dst = (float4*)&Xbuf[(size_t)(1 + 2 * s) * SMAXC + (size_t)row * F + fbase];
        dst[0] = a0; dst[1] = a1;
        *(float4*)&T1[row * 8 + (row & 1) * 4]       = a0;
        *(float4*)&T1[row * 8 + ((row & 1) ^ 1) * 4] = a1;
    }
    __syncthreads();
    // hop 2: X2 = 2 S @ X1 - X0
    float4 b0 = make_float4(0.f, 0.f, 0.f, 0.f);
    float4 b1 = make_float4(0.f, 0.f, 0.f, 0.f);
    for (int p = 0; p < cnt; ++p) {
        int j   = ei[(size_t)p * 1024];
        float v = ev[(size_t)p * 1024];
        float4 x0 = *(float4*)&T1[j * 8 + (j & 1) * 4];
        float4 x1 = *(float4*)&T1[j * 8 + ((j & 1) ^ 1) * 4];
        b0.x += v * x0.x; b0.y += v * x0.y; b0.z += v * x0.z; b0.w += v * x0.w;
        b1.x += v * x1.x; b1.y += v * x1.y; b1.z += v * x1.z; b1.w += v * x1.w;
    }
    {
        float4 p0 = *(float4*)&T0[row * 8 + (row & 1) * 4];
        float4 p1 = *(float4*)&T0[row * 8 + ((row & 1) ^ 1) * 4];
        float4 r0, r1;
        r0.x = 2.f * b0.x - p0.x; r0.y = 2.f * b0.y - p0.y;
        r0.z = 2.f * b0.z - p0.z; r0.w = 2.f * b0.w - p0.w;
        r1.x = 2.f * b1.x - p1.x; r1.y = 2.f * b1.y - p1.y;
        r1.z = 2.f * b1.z - p1.z; r1.w = 2.f * b1.w - p1.w;
        float4* dst = (float4*)&Xbuf[(size_t)(2 + 2 * s) * SMAXC + (size_t)row * F + fbase];
        dst[0] = r0; dst[1] = r1;
    }
}

// ---------------- gate GEMM, k-split 2, partials out ----------------------------
template<bool L0>
__global__ __launch_bounds__(256) void gemm_gate(const float* __restrict__ Xbuf,
                                                 const float* __restrict__ W,
                                                 float* __restrict__ part) {
    constexpr int C    = L0 ? 65 : 128;
    constexpr int Kp   = 5 * C;
    constexpr int KTOT = (Kp + 31) / 32;
    constexpr int KH   = KTOT / 2;
    constexpr int F    = BB * C;
    constexpr int O    = 128;

    __shared__ float  At[32][68];
    __shared__ float4 Ws[32][32];

    int r0 = blockIdx.x * 64;
    int z  = blockIdx.z;
    int kt0 = z ? KH : 0, kt1 = z ? KTOT : KH;
    int tid = threadIdx.x;
    int tx = tid & 15, ty = tid >> 4;

    float acc[4][8];
    #pragma unroll
    for (int i = 0; i < 4; ++i)
        #pragma unroll
        for (int j = 0; j < 8; ++j) acc[i][j] = 0.f;

    for (int kt = kt0; kt < kt1; ++kt) {
        #pragma unroll
        for (int i = 0; i < 8; ++i) {
            int p = i * 256 + tid;
            int kk = p & 31, rr = p >> 5;
            int k = kt * 32 + kk;
            float v = 0.f;
            if (k < Kp) {
                int m, c;
                if (L0) { m = (k * 64528) >> 22; c = k - m * 65; }
                else    { m = k >> 7;            c = k & 127;    }
                int r = r0 + rr;
                v = Xbuf[(size_t)m * SMAXC + (size_t)(r >> 5) * F + (r & 31) * C + c];
            }
            At[kk][rr] = v;
        }
        #pragma unroll
        for (int i = 0; i < 4; ++i) {
            int p = i * 256 + tid;
            int o4 = p & 31, kk = p >> 5;
            int k = kt * 32 + kk;
            float4 vv = make_float4(0.f, 0.f, 0.f, 0.f);
            if (k < Kp) {
                int m, c;
                if (L0) { m = (k * 64528) >> 22; c = k - m * 65; }
                else    { m = k >> 7;            c = k & 127;    }
                vv = *(const float4*)&W[(size_t)(c * 5 + m) * O + o4 * 4];
            }
            Ws[kk][(o4 & 1) * 16 + (o4 >> 1)] = vv;
        }
        __syncthreads();
        #pragma unroll 8
        for (int kk = 0; kk < 32; ++kk) {
            float4 a  = *(float4*)&At[kk][ty * 4];
            float4 w0 = Ws[kk][tx];
            float4 w1 = Ws[kk][tx + 16];
            float av[4] = {a.x, a.y, a.z, a.w};
            #pragma unroll
            for (int i = 0; i < 4; ++i) {
                acc[i][0] += av[i] * w0.x; acc[i][1] += av[i] * w0.y;
                acc[i][2] += av[i] * w0.z; acc[i][3] += av[i] * w0.w;
                acc[i][4] += av[i] * w1.x; acc[i][5] += av[i] * w1.y;
                acc[i][6] += av[i] * w1.z; acc[i][7] += av[i] * w1.w;
            }
        }
        __syncthreads();
    }

    float* dst = part + (size_t)z * RTOT * O;
    int o = tx * 8;
    #pragma unroll
    for (int i = 0; i < 4; ++i) {
        int r = r0 + ty * 4 + i;
        float4 v0 = make_float4(acc[i][0], acc[i][1], acc[i][2], acc[i][3]);
        float4 v1 = make_float4(acc[i][4], acc[i][5], acc[i][6], acc[i][7]);
        *(float4*)&dst[(size_t)r * O + o]     = v0;
        *(float4*)&dst[(size_t)r * O + o + 4] = v1;
    }
}

// ---------------- candidate GEMM, k-split 2, partials out -----------------------
template<bool L0>
__global__ __launch_bounds__(256) void gemm_cand(const float* __restrict__ Xbuf,
                                                 const float* __restrict__ W,
                                                 float* __restrict__ part) {
    constexpr int C    = L0 ? 65 : 128;
    constexpr int Kp   = 5 * C;
    constexpr int KTOT = (Kp + 31) / 32;
    constexpr int KH   = KTOT / 2;
    constexpr int F    = BB * C;
    constexpr int O    = UU;  // 64

    __shared__ float  At[32][68];
    __shared__ float4 Ws[32][16];

    int r0 = blockIdx.x * 64;
    int z  = blockIdx.z;
    int kt0 = z ? KH : 0, kt1 = z ? KTOT : KH;
    int tid = threadIdx.x;
    int tx = tid & 15, ty = tid >> 4;

    float acc[4][4];
    #pragma unroll
    for (int i = 0; i < 4; ++i)
        #pragma unroll
        for (int j = 0; j < 4; ++j) acc[i][j] = 0.f;

    for (int kt = kt0; kt < kt1; ++kt) {
        #pragma unroll
        for (int i = 0; i < 8; ++i) {
            int p = i * 256 + tid;
            int kk = p & 31, rr = p >> 5;
            int k = kt * 32 + kk;
            float v = 0.f;
            if (k < Kp) {
                int m, c;
                if (L0) { m = (k * 64528) >> 22; c = k - m * 65; }
                else    { m = k >> 7;            c = k & 127;    }
                int r = r0 + rr;
                v = Xbuf[(size_t)m * SMAXC + (size_t)(r >> 5) * F + (r & 31) * C + c];
            }
            At[kk][rr] = v;
        }
        #pragma unroll
        for (int i = 0; i < 2; ++i) {
            int p = i * 256 + tid;
            int o4 = p & 15, kk = p >> 4;
            int k = kt * 32 + kk;
            float4 vv = make_float4(0.f, 0.f, 0.f, 0.f);
            if (k < Kp) {
                int m, c;
                if (L0) { m = (k * 64528) >> 22; c = k - m * 65; }
                else    { m = k >> 7;            c = k & 127;    }
                vv = *(const float4*)&W[(size_t)(c * 5 + m) * O + o4 * 4];
            }
            Ws[kk][o4] = vv;
        }
        __syncthreads();
        #pragma unroll 8
        for (int kk = 0; kk < 32; ++kk) {
            float4 a = *(float4*)&At[kk][ty * 4];
            float4 w = Ws[kk][tx];
            float av[4] = {a.x, a.y, a.z, a.w};
            #pragma unroll
            for (int i = 0; i < 4; ++i) {
                acc[i][0] += av[i] * w.x; acc[i][1] += av[i] * w.y;
                acc[i][2] += av[i] * w.z; acc[i][3] += av[i] * w.w;
            }
        }
        __syncthreads();
    }

    float* dst = part + (size_t)z * RTOT * O;
    int o = tx * 4;
    #pragma unroll
    for (int i = 0; i < 4; ++i) {
        int r = r0 + ty * 4 + i;
        float4 v0 = make_float4(acc[i][0], acc[i][1], acc[i][2], acc[i][3]);
        *(float4*)&dst[(size_t)r * O + o] = v0;
    }
}

// ---------------- cand reduce + tanh + GRU update (u recomputed from pg) --------
__global__ __launch_bounds__(256) void reduce_cand(const float* __restrict__ pc,
                                                   const float* __restrict__ pg,
                                                   const float* __restrict__ bg,
                                                   const float* __restrict__ bc,
                                                   float* __restrict__ h) {
    int fid = blockIdx.x * 256 + threadIdx.x;    // RTOT*16 float4 slots
    if (fid >= RTOT * 16) return;
    int r = fid >> 4, q = fid & 15;
    float4 c0 = *(const float4*)&pc[(size_t)r * 64 + q * 4];
    float4 c1 = *(const float4*)&pc[(size_t)(RTOT + r) * 64 + q * 4];
    float4 g0 = *(const float4*)&pg[(size_t)r * 128 + 64 + q * 4];
    float4 g1 = *(const float4*)&pg[(size_t)(RTOT + r) * 128 + 64 + q * 4];
    float4 bcv = *(const float4*)&bc[q * 4];
    float4 bgv = *(const float4*)&bg[64 + q * 4];
    float4* hp = (float4*)&h[(size_t)r * 64 + q * 4];
    float4 hv = *hp;
    float cx = tanhf(c0.x + c1.x + bcv.x), cy = tanhf(c0.y + c1.y + bcv.y);
    float cz = tanhf(c0.z + c1.z + bcv.z), cw = tanhf(c0.w + c1.w + bcv.w);
    float ux = sigm(g0.x + g1.x + bgv.x), uy = sigm(g0.y + g1.y + bgv.y);
    float uz = sigm(g0.z + g1.z + bgv.z), uw = sigm(g0.w + g1.w + bgv.w);
    hv.x = ux * hv.x + (1.f - ux) * cx;
    hv.y = uy * hv.y + (1.f - uy) * cy;
    hv.z = uz * hv.z + (1.f - uz) * cz;
    hv.w = uw * hv.w + (1.f - uw) * cw;
    *hp = hv;
}

// ---------------- projection ----------------------------------------------------
__global__ void proj_kernel(const float* __restrict__ h1, const float* __restrict__ pW,
                            const float* __restrict__ pb, float* __restrict__ outt) {
    int r = blockIdx.x * 256 + threadIdx.x;
    if (r >= RTOT) return;
    int n = r >> 5, b = r & 31;
    const float4* hp = (const float4*)&h1[(size_t)r * UU];
    float acc = pb[0];
    #pragma unroll
    for (int u4 = 0; u4 < 16; ++u4) {
        float4 hv = hp[u4];
        float4 wv = *(const float4*)&pW[u4 * 4];
        acc += hv.x * wv.x + hv.y * wv.y + hv.z * wv.z + hv.w * wv.w;
    }
    outt[b * NN + n] = acc;
}

// ================================================================================
extern "C" void kernel_launch(void* const* d_in, const int* in_sizes, int n_in,
                              void* d_out, int out_size, void* d_ws, size_t ws_size,
                              hipStream_t stream) {
    const float* inputs   = (const float*)d_in[0];
    const float* supports = (const float*)d_in[1];
    const float* enc0_Wg = (const float*)d_in[2];
    const float* enc0_bg = (const float*)d_in[3];
    const float* enc0_Wc = (const float*)d_in[4];
    const float* enc0_bc = (const float*)d_in[5];
    const float* enc1_Wg = (const float*)d_in[6];
    const float* enc1_bg = (const float*)d_in[7];
    const float* enc1_Wc = (const float*)d_in[8];
    const float* enc1_bc = (const float*)d_in[9];
    const float* dec0_Wg = (const float*)d_in[10];
    const float* dec0_bg = (const float*)d_in[11];
    const float* dec0_Wc = (const float*)d_in[12];
    const float* dec0_bc = (const float*)d_in[13];
    const float* dec1_Wg = (const float*)d_in[14];
    const float* dec1_bg = (const float*)d_in[15];
    const float* dec1_Wc = (const float*)d_in[16];
    const float* dec1_bc = (const float*)d_in[17];
    const float* projW   = (const float*)d_in[18];
    const float* projb   = (const float*)d_in[19];
    float* out = (float*)d_out;

    char* wsb = (char*)d_ws;
    size_t off = 0;
    auto alloc = [&](size_t bytes) -> char* {
        char* p = wsb + off;
        off = (off + bytes + 255) & ~(size_t)255;
        return p;
    };
    int*   eidxT = (int*)alloc((size_t)CAP * 1024 * 4);
    float* evalT = (float*)alloc((size_t)CAP * 1024 * 4);
    int*   ecnt  = (int*)alloc((size_t)2 * NN * 4);
    float* h0    = (float*)alloc((size_t)RTOT * UU * 4);
    float* h1    = (float*)alloc((size_t)RTOT * UU * 4);
    float* xzero = (float*)alloc((size_t)RTOT * 4);
    float* pg    = (float*)alloc((size_t)2 * RTOT * 128 * 4);
    float* pc    = (float*)alloc((size_t)2 * RTOT * 64 * 4);
    float* Xbuf  = (float*)alloc((size_t)5 * SMAXC * 4);
    if (off > ws_size) return;

    build_ell<<<256, 256, 0, stream>>>(supports, eidxT, evalT, ecnt);
    {
        int nz = RTOT * UU * 2 + RTOT;  // h0, h1, xzero contiguous
        zero_kernel<<<(nz + 255) / 256, 256, 0, stream>>>(h0, nz);
    }

    auto cell_l0 = [&](const float* x_bn, float* h, const float* Wgp, const float* bgp,
                       const float* Wcp, const float* bcp) {
        dim3 dg(130, 2, 2);
        diffuse<true><<<dg, 512, 0, stream>>>(x_bn, h, nullptr, nullptr, Xbuf, eidxT, evalT, ecnt);
        gemm_gate<true><<<dim3(256, 1, 2), 256, 0, stream>>>(Xbuf, Wgp, pg);
        diffuse<true><<<dg, 512, 0, stream>>>(x_bn, h, pg, bgp, Xbuf, eidxT, evalT, ecnt);
        gemm_cand<true><<<dim3(256, 1, 2), 256, 0, stream>>>(Xbuf, Wcp, pc);
        reduce_cand<<<RTOT * 16 / 256, 256, 0, stream>>>(pc, pg, bgp, bcp, h);
    };
    auto cell_l1 = [&](const float* hin, float* h, const float* Wgp, const float* bgp,
                       const float* Wcp, const float* bcp) {
        dim3 dg(256, 2, 2);
        diffuse<false><<<dg, 512, 0, stream>>>(hin, h, nullptr, nullptr, Xbuf, eidxT, evalT, ecnt);
        gemm_gate<false><<<dim3(256, 1, 2), 256, 0, stream>>>(Xbuf, Wgp, pg);
        diffuse<false><<<dg, 512, 0, stream>>>(hin, h, pg, bgp, Xbuf, eidxT, evalT, ecnt);
        gemm_cand<false><<<dim3(256, 1, 2), 256, 0, stream>>>(Xbuf, Wcp, pc);
        reduce_cand<<<RTOT * 16 / 256, 256, 0, stream>>>(pc, pg, bgp, bcp, h);
    };

    for (int t = 0; t < TT; ++t) {
        cell_l0(inputs + (size_t)t * BB * NN, h0, enc0_Wg, enc0_bg, enc0_Wc, enc0_bc);
        cell_l1(h0, h1, enc1_Wg, enc1_bg, enc1_Wc, enc1_bc);
    }
    for (int t = 0; t < HH; ++t) {
        const float* xin = (t == 0) ? xzero : (out + (size_t)(t - 1) * BB * NN);
        cell_l0(xin, h0, dec0_Wg, dec0_bg, dec0_Wc, dec0_bc);
        cell_l1(h0, h1, dec1_Wg, dec1_bg, dec1_Wc, dec1_bc);
        proj_kernel<<<(RTOT + 255) / 256, 256, 0, stream>>>(h1, projW, projb,
                                                            out + (size_t)t * BB * NN);
    }
}

// Round 5
// 7130.779 us; speedup vs baseline: 1.9970x; 1.0986x over previous
//
#include <hip/hip_runtime.h>
#include <math.h>

#define NN 512
#define BB 32
#define TT 12
#define HH 12
#define UU 64
#define CAP 128
#define RTOT (NN * BB)          // 16384 rows
#define SMAXC (512 * 4096)      // slot stride in Xbuf (floats)
#define ZS 4                    // GEMM k-split

__device__ __forceinline__ float sigm(float x) { return 1.f / (1.f + expf(-x)); }

// ---------------- ELL build (transposed layout): one wave per row ---------------
__global__ __launch_bounds__(256) void build_ell(const float* __restrict__ supports,
                                                 int* __restrict__ eidxT,
                                                 float* __restrict__ evalT,
                                                 int* __restrict__ ecnt) {
    int wave = (blockIdx.x * blockDim.x + threadIdx.x) >> 6;
    int lane = threadIdx.x & 63;
    if (wave >= 2 * NN) return;
    const float* row = supports + (size_t)wave * NN;
    int base = 0;
    for (int k = 0; k < NN / 64; ++k) {
        float v = row[k * 64 + lane];
        unsigned long long m = __ballot(v != 0.0f);
        int pre = __popcll(m & ((1ull << lane) - 1ull));
        if (v != 0.0f) {
            int pos = base + pre;
            if (pos < CAP) {
                eidxT[(size_t)pos * 1024 + wave] = k * 64 + lane;
                evalT[(size_t)pos * 1024 + wave] = v;
            }
        }
        base += __popcll(m);
    }
    if (lane == 0) ecnt[wave] = base < CAP ? base : CAP;
}

__global__ void zero_kernel(float* __restrict__ p, int n) {
    int i = blockIdx.x * 256 + threadIdx.x;
    if (i < n) p[i] = 0.0f;
}

// ---------------- fused diffusion ----------------------------------------------
// pg != null: h-part gated by sigmoid(sum_z pg[z] + bg)  (r-gate fusion)
// half=1 (l1 cand only): cover only c>=64 column tiles; x-half slots reused.
template<bool L0>
__global__ __launch_bounds__(512) void diffuse(const float* __restrict__ xsrc,
                                               const float* __restrict__ hst,
                                               const float* __restrict__ pg,
                                               const float* __restrict__ bg,
                                               float* __restrict__ Xbuf,
                                               const int* __restrict__ eidxT,
                                               const float* __restrict__ evalT,
                                               const int* __restrict__ ecnt,
                                               int half) {
    constexpr int C = L0 ? 65 : 128;
    constexpr int F = BB * C;
    __shared__ float T0[512 * 8];
    __shared__ float T1[512 * 8];
    int bx = blockIdx.x;
    int ft = half ? ((bx >> 2) * 8 + 4 + (bx & 3)) : bx;
    int fbase = ft * 16 + blockIdx.y * 8;
    int s = blockIdx.z;
    int tid = threadIdx.x;

    #pragma unroll
    for (int i = 0; i < 8; ++i) {
        int t = i * 512 + tid;
        int n = t >> 3, fi = t & 7;
        int f = fbase + fi;
        int b, c;
        if (L0) { b = (f * 64528) >> 22; c = f - b * 65; }
        else    { b = f >> 7;            c = f & 127;    }
        float v;
        if (L0) {
            if (c == 0) v = xsrc[b * NN + n];
            else {
                int u = c - 1;
                int r = n * BB + b;
                v = hst[(size_t)r * UU + u];
                if (pg) {
                    float gs = bg[u];
                    #pragma unroll
                    for (int z = 0; z < ZS; ++z)
                        gs += pg[((size_t)z * RTOT + r) * 128 + u];
                    v *= sigm(gs);
                }
            }
        } else {
            int r = n * BB + b;
            if (c < UU) v = xsrc[(size_t)r * UU + c];
            else {
                int u = c - UU;
                v = hst[(size_t)r * UU + u];
                if (pg) {
                    float gs = bg[u];
                    #pragma unroll
                    for (int z = 0; z < ZS; ++z)
                        gs += pg[((size_t)z * RTOT + r) * 128 + u];
                    v *= sigm(gs);
                }
            }
        }
        T0[n * 8 + (((fi >> 2) ^ n) & 1) * 4 + (fi & 3)] = v;
    }
    __syncthreads();

    int row = tid;
    if (s == 0) {
        float4 v0 = *(float4*)&T0[row * 8 + (row & 1) * 4];
        float4 v1 = *(float4*)&T0[row * 8 + ((row & 1) ^ 1) * 4];
        float4* dst = (float4*)&Xbuf[(size_t)row * F + fbase];
        dst[0] = v0; dst[1] = v1;
    }

    int erow = s * NN + row;
    int cnt = ecnt[erow];
    const int*   ei = eidxT + erow;
    const float* ev = evalT + erow;

    // hop 1: X1 = S @ X0
    float4 a0 = make_float4(0.f, 0.f, 0.f, 0.f);
    float4 a1 = make_float4(0.f, 0.f, 0.f, 0.f);
    {
        int p = 0;
        for (; p + 4 <= cnt; p += 4) {
            int j0 = ei[(size_t)(p + 0) * 1024], j1 = ei[(size_t)(p + 1) * 1024];
            int j2 = ei[(size_t)(p + 2) * 1024], j3 = ei[(size_t)(p + 3) * 1024];
            float v0 = ev[(size_t)(p + 0) * 1024], v1 = ev[(size_t)(p + 1) * 1024];
            float v2 = ev[(size_t)(p + 2) * 1024], v3 = ev[(size_t)(p + 3) * 1024];
            float4 xa, xb;
            xa = *(float4*)&T0[j0 * 8 + (j0 & 1) * 4]; xb = *(float4*)&T0[j0 * 8 + ((j0 & 1) ^ 1) * 4];
            a0.x += v0 * xa.x; a0.y += v0 * xa.y; a0.z += v0 * xa.z; a0.w += v0 * xa.w;
            a1.x += v0 * xb.x; a1.y += v0 * xb.y; a1.z += v0 * xb.z; a1.w += v0 * xb.w;
            xa = *(float4*)&T0[j1 * 8 + (j1 & 1) * 4]; xb = *(float4*)&T0[j1 * 8 + ((j1 & 1) ^ 1) * 4];
            a0.x += v1 * xa.x; a0.y += v1 * xa.y; a0.z += v1 * xa.z; a0.w += v1 * xa.w;
            a1.x += v1 * xb.x; a1.y += v1 * xb.y; a1.z += v1 * xb.z; a1.w += v1 * xb.w;
            xa = *(float4*)&T0[j2 * 8 + (j2 & 1) * 4]; xb = *(float4*)&T0[j2 * 8 + ((j2 & 1) ^ 1) * 4];
            a0.x += v2 * xa.x; a0.y += v2 * xa.y; a0.z += v2 * xa.z; a0.w += v2 * xa.w;
            a1.x += v2 * xb.x; a1.y += v2 * xb.y; a1.z += v2 * xb.z; a1.w += v2 * xb.w;
            xa = *(float4*)&T0[j3 * 8 + (j3 & 1) * 4]; xb = *(float4*)&T0[j3 * 8 + ((j3 & 1) ^ 1) * 4];
            a0.x += v3 * xa.x; a0.y += v3 * xa.y; a0.z += v3 * xa.z; a0.w += v3 * xa.w;
            a1.x += v3 * xb.x; a1.y += v3 * xb.y; a1.z += v3 * xb.z; a1.w += v3 * xb.w;
        }
        for (; p < cnt; ++p) {
            int j = ei[(size_t)p * 1024]; float v = ev[(size_t)p * 1024];
            float4 xa = *(float4*)&T0[j * 8 + (j & 1) * 4];
            float4 xb = *(float4*)&T0[j * 8 + ((j & 1) ^ 1) * 4];
            a0.x += v * xa.x; a0.y += v * xa.y; a0.z += v * xa.z; a0.w += v * xa.w;
            a1.x += v * xb.x; a1.y += v * xb.y; a1.z += v * xb.z; a1.w += v * xb.w;
        }
    }
    {
        float4* dst = (float4*)&Xbuf[(size_t)(1 + 2 * s) * SMAXC + (size_t)row * F + fbase];
        dst[0] = a0; dst[1] = a1;
        *(float4*)&T1[row * 8 + (row & 1) * 4]       = a0;
        *(float4*)&T1[row * 8 + ((row & 1) ^ 1) * 4] = a1;
    }
    __syncthreads();
    // hop 2: X2 = 2 S @ X1 - X0
    float4 b0 = make_float4(0.f, 0.f, 0.f, 0.f);
    float4 b1 = make_float4(0.f, 0.f, 0.f, 0.f);
    {
        int p = 0;
        for (; p + 4 <= cnt; p += 4) {
            int j0 = ei[(size_t)(p + 0) * 1024], j1 = ei[(size_t)(p + 1) * 1024];
            int j2 = ei[(size_t)(p + 2) * 1024], j3 = ei[(size_t)(p + 3) * 1024];
            float v0 = ev[(size_t)(p + 0) * 1024], v1 = ev[(size_t)(p + 1) * 1024];
            float v2 = ev[(size_t)(p + 2) * 1024], v3 = ev[(size_t)(p + 3) * 1024];
            float4 xa, xb;
            xa = *(float4*)&T1[j0 * 8 + (j0 & 1) * 4]; xb = *(float4*)&T1[j0 * 8 + ((j0 & 1) ^ 1) * 4];
            b0.x += v0 * xa.x; b0.y += v0 * xa.y; b0.z += v0 * xa.z; b0.w += v0 * xa.w;
            b1.x += v0 * xb.x; b1.y += v0 * xb.y; b1.z += v0 * xb.z; b1.w += v0 * xb.w;
            xa = *(float4*)&T1[j1 * 8 + (j1 & 1) * 4]; xb = *(float4*)&T1[j1 * 8 + ((j1 & 1) ^ 1) * 4];
            b0.x += v1 * xa.x; b0.y += v1 * xa.y; b0.z += v1 * xa.z; b0.w += v1 * xa.w;
            b1.x += v1 * xb.x; b1.y += v1 * xb.y; b1.z += v1 * xb.z; b1.w += v1 * xb.w;
            xa = *(float4*)&T1[j2 * 8 + (j2 & 1) * 4]; xb = *(float4*)&T1[j2 * 8 + ((j2 & 1) ^ 1) * 4];
            b0.x += v2 * xa.x; b0.y += v2 * xa.y; b0.z += v2 * xa.z; b0.w += v2 * xa.w;
            b1.x += v2 * xb.x; b1.y += v2 * xb.y; b1.z += v2 * xb.z; b1.w += v2 * xb.w;
            xa = *(float4*)&T1[j3 * 8 + (j3 & 1) * 4]; xb = *(float4*)&T1[j3 * 8 + ((j3 & 1) ^ 1) * 4];
            b0.x += v3 * xa.x; b0.y += v3 * xa.y; b0.z += v3 * xa.z; b0.w += v3 * xa.w;
            b1.x += v3 * xb.x; b1.y += v3 * xb.y; b1.z += v3 * xb.z; b1.w += v3 * xb.w;
        }
        for (; p < cnt; ++p) {
            int j = ei[(size_t)p * 1024]; float v = ev[(size_t)p * 1024];
            float4 xa = *(float4*)&T1[j * 8 + (j & 1) * 4];
            float4 xb = *(float4*)&T1[j * 8 + ((j & 1) ^ 1) * 4];
            b0.x += v * xa.x; b0.y += v * xa.y; b0.z += v * xa.z; b0.w += v * xa.w;
            b1.x += v * xb.x; b1.y += v * xb.y; b1.z += v * xb.z; b1.w += v * xb.w;
        }
    }
    {
        float4 p0 = *(float4*)&T0[row * 8 + (row & 1) * 4];
        float4 p1 = *(float4*)&T0[row * 8 + ((row & 1) ^ 1) * 4];
        float4 r0, r1;
        r0.x = 2.f * b0.x - p0.x; r0.y = 2.f * b0.y - p0.y;
        r0.z = 2.f * b0.z - p0.z; r0.w = 2.f * b0.w - p0.w;
        r1.x = 2.f * b1.x - p1.x; r1.y = 2.f * b1.y - p1.y;
        r1.z = 2.f * b1.z - p1.z; r1.w = 2.f * b1.w - p1.w;
        float4* dst = (float4*)&Xbuf[(size_t)(2 + 2 * s) * SMAXC + (size_t)row * F + fbase];
        dst[0] = r0; dst[1] = r1;
    }
}

// ---------------- gate GEMM, k-split ZS, partials out ---------------------------
template<bool L0>
__global__ __launch_bounds__(256) void gemm_gate(const float* __restrict__ Xbuf,
                                                 const float* __restrict__ W,
                                                 float* __restrict__ part) {
    constexpr int C    = L0 ? 65 : 128;
    constexpr int Kp   = 5 * C;
    constexpr int KTOT = (Kp + 31) / 32;
    constexpr int F    = BB * C;
    constexpr int O    = 128;

    __shared__ float  At[32][68];
    __shared__ float4 Ws[32][32];

    int r0 = blockIdx.x * 64;
    int z  = blockIdx.z;
    int kt0 = (z * KTOT) >> 2, kt1 = ((z + 1) * KTOT) >> 2;
    int tid = threadIdx.x;
    int tx = tid & 15, ty = tid >> 4;

    float acc[4][8];
    #pragma unroll
    for (int i = 0; i < 4; ++i)
        #pragma unroll
        for (int j = 0; j < 8; ++j) acc[i][j] = 0.f;

    for (int kt = kt0; kt < kt1; ++kt) {
        #pragma unroll
        for (int i = 0; i < 8; ++i) {
            int p = i * 256 + tid;
            int kk = p & 31, rr = p >> 5;
            int k = kt * 32 + kk;
            float v = 0.f;
            if (k < Kp) {
                int m, c;
                if (L0) { m = (k * 64528) >> 22; c = k - m * 65; }
                else    { m = k >> 7;            c = k & 127;    }
                int r = r0 + rr;
                v = Xbuf[(size_t)m * SMAXC + (size_t)(r >> 5) * F + (r & 31) * C + c];
            }
            At[kk][rr] = v;
        }
        #pragma unroll
        for (int i = 0; i < 4; ++i) {
            int p = i * 256 + tid;
            int o4 = p & 31, kk = p >> 5;
            int k = kt * 32 + kk;
            float4 vv = make_float4(0.f, 0.f, 0.f, 0.f);
            if (k < Kp) {
                int m, c;
                if (L0) { m = (k * 64528) >> 22; c = k - m * 65; }
                else    { m = k >> 7;            c = k & 127;    }
                vv = *(const float4*)&W[(size_t)(c * 5 + m) * O + o4 * 4];
            }
            Ws[kk][(o4 & 1) * 16 + (o4 >> 1)] = vv;
        }
        __syncthreads();
        #pragma unroll 8
        for (int kk = 0; kk < 32; ++kk) {
            float4 a  = *(float4*)&At[kk][ty * 4];
            float4 w0 = Ws[kk][tx];
            float4 w1 = Ws[kk][tx + 16];
            float av[4] = {a.x, a.y, a.z, a.w};
            #pragma unroll
            for (int i = 0; i < 4; ++i) {
                acc[i][0] += av[i] * w0.x; acc[i][1] += av[i] * w0.y;
                acc[i][2] += av[i] * w0.z; acc[i][3] += av[i] * w0.w;
                acc[i][4] += av[i] * w1.x; acc[i][5] += av[i] * w1.y;
                acc[i][6] += av[i] * w1.z; acc[i][7] += av[i] * w1.w;
            }
        }
        __syncthreads();
    }

    float* dst = part + (size_t)z * RTOT * O;
    int o = tx * 8;
    #pragma unroll
    for (int i = 0; i < 4; ++i) {
        int r = r0 + ty * 4 + i;
        *(float4*)&dst[(size_t)r * O + o]     = make_float4(acc[i][0], acc[i][1], acc[i][2], acc[i][3]);
        *(float4*)&dst[(size_t)r * O + o + 4] = make_float4(acc[i][4], acc[i][5], acc[i][6], acc[i][7]);
    }
}

// ---------------- candidate GEMM, k-split ZS, partials out ----------------------
template<bool L0>
__global__ __launch_bounds__(256) void gemm_cand(const float* __restrict__ Xbuf,
                                                 const float* __restrict__ W,
                                                 float* __restrict__ part) {
    constexpr int C    = L0 ? 65 : 128;
    constexpr int Kp   = 5 * C;
    constexpr int KTOT = (Kp + 31) / 32;
    constexpr int F    = BB * C;
    constexpr int O    = UU;  // 64

    __shared__ float  At[32][68];
    __shared__ float4 Ws[32][16];

    int r0 = blockIdx.x * 64;
    int z  = blockIdx.z;
    int kt0 = (z * KTOT) >> 2, kt1 = ((z + 1) * KTOT) >> 2;
    int tid = threadIdx.x;
    int tx = tid & 15, ty = tid >> 4;

    float acc[4][4];
    #pragma unroll
    for (int i = 0; i < 4; ++i)
        #pragma unroll
        for (int j = 0; j < 4; ++j) acc[i][j] = 0.f;

    for (int kt = kt0; kt < kt1; ++kt) {
        #pragma unroll
        for (int i = 0; i < 8; ++i) {
            int p = i * 256 + tid;
            int kk = p & 31, rr = p >> 5;
            int k = kt * 32 + kk;
            float v = 0.f;
            if (k < Kp) {
                int m, c;
                if (L0) { m = (k * 64528) >> 22; c = k - m * 65; }
                else    { m = k >> 7;            c = k & 127;    }
                int r = r0 + rr;
                v = Xbuf[(size_t)m * SMAXC + (size_t)(r >> 5) * F + (r & 31) * C + c];
            }
            At[kk][rr] = v;
        }
        #pragma unroll
        for (int i = 0; i < 2; ++i) {
            int p = i * 256 + tid;
            int o4 = p & 15, kk = p >> 4;
            int k = kt * 32 + kk;
            float4 vv = make_float4(0.f, 0.f, 0.f, 0.f);
            if (k < Kp) {
                int m, c;
                if (L0) { m = (k * 64528) >> 22; c = k - m * 65; }
                else    { m = k >> 7;            c = k & 127;    }
                vv = *(const float4*)&W[(size_t)(c * 5 + m) * O + o4 * 4];
            }
            Ws[kk][o4] = vv;
        }
        __syncthreads();
        #pragma unroll 8
        for (int kk = 0; kk < 32; ++kk) {
            float4 a = *(float4*)&At[kk][ty * 4];
            float4 w = Ws[kk][tx];
            float av[4] = {a.x, a.y, a.z, a.w};
            #pragma unroll
            for (int i = 0; i < 4; ++i) {
                acc[i][0] += av[i] * w.x; acc[i][1] += av[i] * w.y;
                acc[i][2] += av[i] * w.z; acc[i][3] += av[i] * w.w;
            }
        }
        __syncthreads();
    }

    float* dst = part + (size_t)z * RTOT * O;
    int o = tx * 4;
    #pragma unroll
    for (int i = 0; i < 4; ++i) {
        int r = r0 + ty * 4 + i;
        *(float4*)&dst[(size_t)r * O + o] = make_float4(acc[i][0], acc[i][1], acc[i][2], acc[i][3]);
    }
}

// ---------------- cand reduce + tanh + GRU update + optional fused proj ---------
__global__ __launch_bounds__(256) void reduce_cand(const float* __restrict__ pc,
                                                   const float* __restrict__ pg,
                                                   const float* __restrict__ bg,
                                                   const float* __restrict__ bc,
                                                   float* __restrict__ h,
                                                   const float* __restrict__ projW,
                                                   const float* __restrict__ projb,
                                                   float* __restrict__ outp) {
    int fid = blockIdx.x * 256 + threadIdx.x;    // RTOT*16 float4 slots
    if (fid >= RTOT * 16) return;
    int r = fid >> 4, q = fid & 15;
    float4 cs = make_float4(0.f, 0.f, 0.f, 0.f);
    float4 gs = make_float4(0.f, 0.f, 0.f, 0.f);
    #pragma unroll
    for (int z = 0; z < ZS; ++z) {
        float4 cz = *(const float4*)&pc[((size_t)z * RTOT + r) * 64 + q * 4];
        float4 gz = *(const float4*)&pg[((size_t)z * RTOT + r) * 128 + 64 + q * 4];
        cs.x += cz.x; cs.y += cz.y; cs.z += cz.z; cs.w += cz.w;
        gs.x += gz.x; gs.y += gz.y; gs.z += gz.z; gs.w += gz.w;
    }
    float4 bcv = *(const float4*)&bc[q * 4];
    float4 bgv = *(const float4*)&bg[64 + q * 4];
    float4* hp = (float4*)&h[(size_t)r * 64 + q * 4];
    float4 hv = *hp;
    float cx = tanhf(cs.x + bcv.x), cy = tanhf(cs.y + bcv.y);
    float cz = tanhf(cs.z + bcv.z), cw = tanhf(cs.w + bcv.w);
    float ux = sigm(gs.x + bgv.x), uy = sigm(gs.y + bgv.y);
    float uz = sigm(gs.z + bgv.z), uw = sigm(gs.w + bgv.w);
    hv.x = ux * hv.x + (1.f - ux) * cx;
    hv.y = uy * hv.y + (1.f - uy) * cy;
    hv.z = uz * hv.z + (1.f - uz) * cz;
    hv.w = uw * hv.w + (1.f - uw) * cw;
    *hp = hv;
    if (outp) {
        float4 wv = *(const float4*)&projW[q * 4];
        float part = hv.x * wv.x + hv.y * wv.y + hv.z * wv.z + hv.w * wv.w;
        part += __shfl_xor(part, 1, 16);
        part += __shfl_xor(part, 2, 16);
        part += __shfl_xor(part, 4, 16);
        part += __shfl_xor(part, 8, 16);
        if (q == 0) {
            int n = r >> 5, b = r & 31;
            outp[b * NN + n] = part + projb[0];
        }
    }
}

// ================================================================================
extern "C" void kernel_launch(void* const* d_in, const int* in_sizes, int n_in,
                              void* d_out, int out_size, void* d_ws, size_t ws_size,
                              hipStream_t stream) {
    const float* inputs   = (const float*)d_in[0];
    const float* supports = (const float*)d_in[1];
    const float* enc0_Wg = (const float*)d_in[2];
    const float* enc0_bg = (const float*)d_in[3];
    const float* enc0_Wc = (const float*)d_in[4];
    const float* enc0_bc = (const float*)d_in[5];
    const float* enc1_Wg = (const float*)d_in[6];
    const float* enc1_bg = (const float*)d_in[7];
    const float* enc1_Wc = (const float*)d_in[8];
    const float* enc1_bc = (const float*)d_in[9];
    const float* dec0_Wg = (const float*)d_in[10];
    const float* dec0_bg = (const float*)d_in[11];
    const float* dec0_Wc = (const float*)d_in[12];
    const float* dec0_bc = (const float*)d_in[13];
    const float* dec1_Wg = (const float*)d_in[14];
    const float* dec1_bg = (const float*)d_in[15];
    const float* dec1_Wc = (const float*)d_in[16];
    const float* dec1_bc = (const float*)d_in[17];
    const float* projW   = (const float*)d_in[18];
    const float* projb   = (const float*)d_in[19];
    float* out = (float*)d_out;

    char* wsb = (char*)d_ws;
    size_t off = 0;
    auto alloc = [&](size_t bytes) -> char* {
        char* p = wsb + off;
        off = (off + bytes + 255) & ~(size_t)255;
        return p;
    };
    int*   eidxT = (int*)alloc((size_t)CAP * 1024 * 4);
    float* evalT = (float*)alloc((size_t)CAP * 1024 * 4);
    int*   ecnt  = (int*)alloc((size_t)2 * NN * 4);
    float* h0    = (float*)alloc((size_t)RTOT * UU * 4);
    float* h1    = (float*)alloc((size_t)RTOT * UU * 4);
    float* xzero = (float*)alloc((size_t)RTOT * 4);
    float* pg    = (float*)alloc((size_t)ZS * RTOT * 128 * 4);
    float* pc    = (float*)alloc((size_t)ZS * RTOT * 64 * 4);
    float* Xbuf  = (float*)alloc((size_t)5 * SMAXC * 4);
    if (off > ws_size) return;

    build_ell<<<256, 256, 0, stream>>>(supports, eidxT, evalT, ecnt);
    {
        int nz = RTOT * UU * 2 + RTOT;  // h0, h1, xzero contiguous
        zero_kernel<<<(nz + 255) / 256, 256, 0, stream>>>(h0, nz);
    }

    auto cell_l0 = [&](const float* x_bn, float* h, const float* Wgp, const float* bgp,
                       const float* Wcp, const float* bcp) {
        dim3 dg(130, 2, 2);
        diffuse<true><<<dg, 512, 0, stream>>>(x_bn, h, nullptr, nullptr, Xbuf, eidxT, evalT, ecnt, 0);
        gemm_gate<true><<<dim3(256, 1, ZS), 256, 0, stream>>>(Xbuf, Wgp, pg);
        diffuse<true><<<dg, 512, 0, stream>>>(x_bn, h, pg, bgp, Xbuf, eidxT, evalT, ecnt, 0);
        gemm_cand<true><<<dim3(256, 1, ZS), 256, 0, stream>>>(Xbuf, Wcp, pc);
        reduce_cand<<<RTOT * 16 / 256, 256, 0, stream>>>(pc, pg, bgp, bcp, h,
                                                         nullptr, nullptr, nullptr);
    };
    auto cell_l1 = [&](const float* hin, float* h, const float* Wgp, const float* bgp,
                       const float* Wcp, const float* bcp, float* outp) {
        diffuse<false><<<dim3(256, 2, 2), 512, 0, stream>>>(hin, h, nullptr, nullptr,
                                                            Xbuf, eidxT, evalT, ecnt, 0);
        gemm_gate<false><<<dim3(256, 1, ZS), 256, 0, stream>>>(Xbuf, Wgp, pg);
        diffuse<false><<<dim3(128, 2, 2), 512, 0, stream>>>(hin, h, pg, bgp,
                                                            Xbuf, eidxT, evalT, ecnt, 1);
        gemm_cand<false><<<dim3(256, 1, ZS), 256, 0, stream>>>(Xbuf, Wcp, pc);
        reduce_cand<<<RTOT * 16 / 256, 256, 0, stream>>>(pc, pg, bgp, bcp, h,
                                                         projW, projb, outp);
    };

    for (int t = 0; t < TT; ++t) {
        cell_l0(inputs + (size_t)t * BB * NN, h0, enc0_Wg, enc0_bg, enc0_Wc, enc0_bc);
        cell_l1(h0, h1, enc1_Wg, enc1_bg, enc1_Wc, enc1_bc, nullptr);
    }
    for (int t = 0; t < HH; ++t) {
        const float* xin = (t == 0) ? xzero : (out + (size_t)(t - 1) * BB * NN);
        cell_l0(xin, h0, dec0_Wg, dec0_bg, dec0_Wc, dec0_bc);
        cell_l1(h0, h1, dec1_Wg, dec1_bg, dec1_Wc, dec1_bc, out + (size_t)t * BB * NN);
    }
}

// Round 6
// 6828.403 us; speedup vs baseline: 2.0854x; 1.0443x over previous
//
#include <hip/hip_runtime.h>
#include <math.h>

#define NN 512
#define BB 32
#define TT 12
#define HH 12
#define UU 64
#define CAP 128
#define RTOT (NN * BB)          // 16384 rows

__device__ __forceinline__ float sigm(float x) { return 1.f / (1.f + expf(-x)); }

// ---------------- ELL build: int2 {idx, val_bits} at [p*1024 + s*512 + row] -----
__global__ __launch_bounds__(256) void build_ell(const float* __restrict__ sup,
                                                 int2* __restrict__ ell,
                                                 int* __restrict__ ecnt) {
    int wave = (blockIdx.x * blockDim.x + threadIdx.x) >> 6;
    int lane = threadIdx.x & 63;
    if (wave >= 2 * NN) return;
    const float* row = sup + (size_t)wave * NN;
    int base = 0;
    for (int k = 0; k < NN / 64; ++k) {
        float v = row[k * 64 + lane];
        unsigned long long m = __ballot(v != 0.0f);
        int pre = __popcll(m & ((1ull << lane) - 1ull));
        if (v != 0.0f) {
            int pos = base + pre;
            if (pos < CAP)
                ell[(size_t)pos * 1024 + wave] = make_int2(k * 64 + lane, __float_as_int(v));
        }
        base += __popcll(m);
    }
    if (lane == 0) ecnt[wave] = base < CAP ? base : CAP;
}

__global__ void zero_kernel(float* __restrict__ p, int n) {
    int i = blockIdx.x * 256 + threadIdx.x;
    if (i < n) p[i] = 0.0f;
}

// ---------------- dense GEMM: Zm = X0 @ Wm --------------------------------------
// X0 rows rb = b*512+n, channels c; A gathered from x / h (layouts [b][u][n]).
// Z layout (W-blocked): Z[((m*32+b)*(OO/WZ) + og)*512*WZ + n*WZ + oi]
template<bool L0, bool GATED, int OO>
__global__ __launch_bounds__(256) void gemm_f(const float* __restrict__ x,
                                              const float* __restrict__ hA,
                                              const float* __restrict__ hB,
                                              const float* __restrict__ g,
                                              const float* __restrict__ W,
                                              float* __restrict__ Z) {
    constexpr int C  = L0 ? 65 : 128;
    constexpr int KT = (C + 31) / 32;
    constexpr int WZ = (OO == 128) ? 8 : 4;
    constexpr int JW = OO / 16;          // o's per thread (8 or 4)

    __shared__ float  At[32][68];
    __shared__ float4 Ws[32][OO / 4];

    int b  = blockIdx.x >> 3;
    int n0 = (blockIdx.x & 7) * 64;
    int m  = blockIdx.y;
    int tid = threadIdx.x, tx = tid & 15, ty = tid >> 4;

    float acc[4][JW];
    #pragma unroll
    for (int i = 0; i < 4; ++i)
        #pragma unroll
        for (int j = 0; j < JW; ++j) acc[i][j] = 0.f;

    for (int kt = 0; kt < KT; ++kt) {
        // A stage: 32 k x 64 n
        #pragma unroll
        for (int i = 0; i < 8; ++i) {
            int p = i * 256 + tid;
            int rr = p & 63, kk = p >> 6;
            int c = kt * 32 + kk;
            float v = 0.f;
            if (c < C) {
                int nn = n0 + rr;
                if (L0) {
                    if (c == 0) v = x[b * 512 + nn];
                    else {
                        int u = c - 1;
                        v = hA[(size_t)((b << 6) + u) * 512 + nn];
                        if (GATED) v *= g[(size_t)((b << 7) + u) * 512 + nn];
                    }
                } else {
                    if (c < 64) v = hA[(size_t)((b << 6) + c) * 512 + nn];
                    else {
                        int u = c - 64;
                        v = hB[(size_t)((b << 6) + u) * 512 + nn];
                        if (GATED) v *= g[(size_t)((b << 7) + u) * 512 + nn];
                    }
                }
            }
            At[kk][rr] = v;
        }
        // W stage
        #pragma unroll
        for (int i = 0; i < OO / 32; ++i) {
            int p = i * 256 + tid;
            int o4 = p & (OO / 4 - 1);
            int kk = (OO == 128) ? (p >> 5) : (p >> 4);
            int c = kt * 32 + kk;
            float4 vv = make_float4(0.f, 0.f, 0.f, 0.f);
            if (c < C) vv = *(const float4*)&W[(size_t)(c * 5 + m) * OO + o4 * 4];
            if (OO == 128) Ws[kk][(o4 & 1) * 16 + (o4 >> 1)] = vv;
            else           Ws[kk][o4] = vv;
        }
        __syncthreads();
        #pragma unroll 8
        for (int kk = 0; kk < 32; ++kk) {
            float4 a = *(float4*)&At[kk][ty * 4];
            float av[4] = {a.x, a.y, a.z, a.w};
            float4 w0 = Ws[kk][tx];
            if (OO == 128) {
                float4 w1 = Ws[kk][tx + 16];
                #pragma unroll
                for (int i = 0; i < 4; ++i) {
                    acc[i][0] += av[i] * w0.x; acc[i][1] += av[i] * w0.y;
                    acc[i][2] += av[i] * w0.z; acc[i][3] += av[i] * w0.w;
                    acc[i][4] += av[i] * w1.x; acc[i][5] += av[i] * w1.y;
                    acc[i][6] += av[i] * w1.z; acc[i][7] += av[i] * w1.w;
                }
            } else {
                #pragma unroll
                for (int i = 0; i < 4; ++i) {
                    acc[i][0] += av[i] * w0.x; acc[i][1] += av[i] * w0.y;
                    acc[i][2] += av[i] * w0.z; acc[i][3] += av[i] * w0.w;
                }
            }
        }
        __syncthreads();
    }
    // epilogue: thread's JW o's live in one W-block og = tx
    float* Zt = Z + ((size_t)(m * 32 + b) * (OO / WZ) + tx) * (512 * WZ);
    #pragma unroll
    for (int i = 0; i < 4; ++i) {
        int nn = n0 + ty * 4 + i;
        *(float4*)&Zt[nn * WZ] = make_float4(acc[i][0], acc[i][1], acc[i][2], acc[i][3]);
        if (OO == 128)
            *(float4*)&Zt[nn * WZ + 4] = make_float4(acc[i][4], acc[i][5], acc[i][6], acc[i][7]);
    }
}

// ---------------- combine: out = Z0 - Z2 - Z4 + S1(Z1+2S1Z2) + S2(Z3+2S2Z4) -----
// MODE 0: gate -> g = sigmoid(out + bg)        (OO=128, W=8)
// MODE 1: cand -> h = u*h + (1-u)*tanh(out+bc) (OO=64,  W=4), u from gin
template<int MODE>
__global__ __launch_bounds__(512) void combine(const float* __restrict__ Z,
                                               const int2* __restrict__ ell,
                                               const int* __restrict__ ecnt,
                                               const float* __restrict__ bias,
                                               float* __restrict__ gout,
                                               const float* __restrict__ gin,
                                               float* __restrict__ h) {
    constexpr int W  = (MODE == 0) ? 8 : 4;
    constexpr int OO = (MODE == 0) ? 128 : 64;
    constexpr size_t TILE = (size_t)512 * W;
    const size_t MS = (size_t)32 * (OO / W) * TILE;

    __shared__ float Ta[512 * W];
    __shared__ float Tb[512 * W];

    int b  = blockIdx.x >> 4;
    int o0 = (blockIdx.x & 15) * W;
    int n  = threadIdx.x;
    const float* Zt = Z + ((size_t)b * (OO / W) + (o0 / W)) * TILE;

    int cnt0 = ecnt[n], cnt1 = ecnt[NN + n];

    auto stage = [&](float* T, int m) {
        const float4* src = (const float4*)(Zt + m * MS);
        if (W == 8) {
            #pragma unroll
            for (int i = 0; i < 2; ++i) {
                int f4 = i * 512 + n;
                int row = f4 >> 1, half = f4 & 1;
                *(float4*)&T[row * 8 + ((half ^ row) & 1) * 4] = src[f4];
            }
        } else {
            *(float4*)&T[n * 4] = src[n];
        }
    };
    auto own_lds = [&](const float* T, float* o) {
        if (W == 8) {
            *(float4*)&o[0] = *(const float4*)&T[n * 8 + (n & 1) * 4];
            *(float4*)&o[4] = *(const float4*)&T[n * 8 + ((n & 1) ^ 1) * 4];
        } else {
            *(float4*)&o[0] = *(const float4*)&T[n * 4];
        }
    };
    auto own_glob = [&](int m, float* o) {
        const float* src = Zt + m * MS + (size_t)n * W;
        *(float4*)&o[0] = *(const float4*)&src[0];
        if (W == 8) *(float4*)&o[4] = *(const float4*)&src[4];
    };
    auto put_own = [&](float* T, const float* y) {
        if (W == 8) {
            *(float4*)&T[n * 8 + (n & 1) * 4]       = *(const float4*)&y[0];
            *(float4*)&T[n * 8 + ((n & 1) ^ 1) * 4] = *(const float4*)&y[4];
        } else {
            *(float4*)&T[n * 4] = *(const float4*)&y[0];
        }
    };
    auto gather = [&](const float* T, int s, float* o) {
        int cnt = s ? cnt1 : cnt0;
        const int2* e0 = ell + s * NN + n;
        float4 a0 = make_float4(0.f, 0.f, 0.f, 0.f);
        float4 a1 = make_float4(0.f, 0.f, 0.f, 0.f);
        for (int p = 0; p < cnt; ++p) {
            int2 e = e0[(size_t)p << 10];
            int j = e.x;
            float v = __int_as_float(e.y);
            if (W == 8) {
                float4 x0 = *(const float4*)&T[j * 8 + (j & 1) * 4];
                float4 x1 = *(const float4*)&T[j * 8 + ((j & 1) ^ 1) * 4];
                a0.x += v * x0.x; a0.y += v * x0.y; a0.z += v * x0.z; a0.w += v * x0.w;
                a1.x += v * x1.x; a1.y += v * x1.y; a1.z += v * x1.z; a1.w += v * x1.w;
            } else {
                float4 x0 = *(const float4*)&T[j * 4];
                a0.x += v * x0.x; a0.y += v * x0.y; a0.z += v * x0.z; a0.w += v * x0.w;
            }
        }
        *(float4*)&o[0] = a0;
        if (W == 8) *(float4*)&o[4] = a1;
    };

    float z2own[W], z4own[W], y[W], g2[W], g4[W], t1[W];

    stage(Ta, 2);                       // Z2
    __syncthreads();
    own_lds(Ta, z2own);
    gather(Ta, 0, t1);                  // S1 Z2
    own_glob(1, y);                     // Z1
    #pragma unroll
    for (int fi = 0; fi < W; ++fi) y[fi] += 2.f * t1[fi];
    __syncthreads();                    // all gathers on Ta done
    put_own(Tb, y);
    __syncthreads();
    gather(Tb, 0, g2);                  // S1 (Z1 + 2 S1 Z2)
    __syncthreads();                    // all gathers on Tb done
    stage(Ta, 4);                       // Z4
    own_glob(3, y);                     // Z3
    __syncthreads();
    own_lds(Ta, z4own);
    gather(Ta, 1, t1);                  // S2 Z4
    #pragma unroll
    for (int fi = 0; fi < W; ++fi) y[fi] += 2.f * t1[fi];
    __syncthreads();
    put_own(Tb, y);
    __syncthreads();
    gather(Tb, 1, g4);                  // S2 (Z3 + 2 S2 Z4)
    own_glob(0, t1);                    // Z0

    #pragma unroll
    for (int fi = 0; fi < W; ++fi) {
        float acc = t1[fi] - z2own[fi] - z4own[fi] + g2[fi] + g4[fi] + bias[o0 + fi];
        if (MODE == 0) {
            gout[(size_t)((b << 7) + o0 + fi) * 512 + n] = sigm(acc);
        } else {
            float u  = gin[(size_t)((b << 7) + 64 + o0 + fi) * 512 + n];
            float* hp = &h[(size_t)((b << 6) + o0 + fi) * 512 + n];
            float cv = tanhf(acc);
            *hp = u * (*hp) + (1.f - u) * cv;
        }
    }
}

// ---------------- projection ----------------------------------------------------
__global__ void proj_kernel(const float* __restrict__ h1, const float* __restrict__ pW,
                            const float* __restrict__ pb, float* __restrict__ outt) {
    int r = blockIdx.x * 256 + threadIdx.x;
    if (r >= RTOT) return;
    int b = r >> 9, n = r & 511;
    float acc = pb[0];
    #pragma unroll 16
    for (int u = 0; u < 64; ++u)
        acc += h1[(size_t)((b << 6) + u) * 512 + n] * pW[u];
    outt[b * NN + n] = acc;
}

// ================================================================================
extern "C" void kernel_launch(void* const* d_in, const int* in_sizes, int n_in,
                              void* d_out, int out_size, void* d_ws, size_t ws_size,
                              hipStream_t stream) {
    const float* inputs   = (const float*)d_in[0];
    const float* supports = (const float*)d_in[1];
    const float* enc0_Wg = (const float*)d_in[2];
    const float* enc0_bg = (const float*)d_in[3];
    const float* enc0_Wc = (const float*)d_in[4];
    const float* enc0_bc = (const float*)d_in[5];
    const float* enc1_Wg = (const float*)d_in[6];
    const float* enc1_bg = (const float*)d_in[7];
    const float* enc1_Wc = (const float*)d_in[8];
    const float* enc1_bc = (const float*)d_in[9];
    const float* dec0_Wg = (const float*)d_in[10];
    const float* dec0_bg = (const float*)d_in[11];
    const float* dec0_Wc = (const float*)d_in[12];
    const float* dec0_bc = (const float*)d_in[13];
    const float* dec1_Wg = (const float*)d_in[14];
    const float* dec1_bg = (const float*)d_in[15];
    const float* dec1_Wc = (const float*)d_in[16];
    const float* dec1_bc = (const float*)d_in[17];
    const float* projW   = (const float*)d_in[18];
    const float* projb   = (const float*)d_in[19];
    float* out = (float*)d_out;

    char* wsb = (char*)d_ws;
    size_t off = 0;
    auto alloc = [&](size_t bytes) -> char* {
        char* p = wsb + off;
        off = (off + bytes + 255) & ~(size_t)255;
        return p;
    };
    int2*  ell   = (int2*)alloc((size_t)CAP * 1024 * 8);
    int*   ecnt  = (int*)alloc((size_t)2 * NN * 4);
    float* h0    = (float*)alloc((size_t)RTOT * UU * 4);     // [b][u][n]
    float* h1    = (float*)alloc((size_t)RTOT * UU * 4);
    float* xzero = (float*)alloc((size_t)RTOT * 4);
    float* g     = (float*)alloc((size_t)RTOT * 128 * 4);    // [b][go][n]
    float* Z     = (float*)alloc((size_t)5 * RTOT * 128 * 4);
    if (off > ws_size) return;

    build_ell<<<256, 256, 0, stream>>>(supports, ell, ecnt);
    {
        int nz = RTOT * UU * 2 + RTOT;  // h0, h1, xzero contiguous
        zero_kernel<<<(nz + 255) / 256, 256, 0, stream>>>(h0, nz);
    }

    auto cell_l0 = [&](const float* x_bn, float* h, const float* Wgp, const float* bgp,
                       const float* Wcp, const float* bcp) {
        gemm_f<true, false, 128><<<dim3(256, 5), 256, 0, stream>>>(x_bn, h, nullptr, nullptr, Wgp, Z);
        combine<0><<<512, 512, 0, stream>>>(Z, ell, ecnt, bgp, g, nullptr, nullptr);
        gemm_f<true, true, 64><<<dim3(256, 5), 256, 0, stream>>>(x_bn, h, nullptr, g, Wcp, Z);
        combine<1><<<512, 512, 0, stream>>>(Z, ell, ecnt, bcp, nullptr, g, h);
    };
    auto cell_l1 = [&](const float* hin, float* h, const float* Wgp, const float* bgp,
                       const float* Wcp, const float* bcp) {
        gemm_f<false, false, 128><<<dim3(256, 5), 256, 0, stream>>>(nullptr, hin, h, nullptr, Wgp, Z);
        combine<0><<<512, 512, 0, stream>>>(Z, ell, ecnt, bgp, g, nullptr, nullptr);
        gemm_f<false, true, 64><<<dim3(256, 5), 256, 0, stream>>>(nullptr, hin, h, g, Wcp, Z);
        combine<1><<<512, 512, 0, stream>>>(Z, ell, ecnt, bcp, nullptr, g, h);
    };

    for (int t = 0; t < TT; ++t) {
        cell_l0(inputs + (size_t)t * BB * NN, h0, enc0_Wg, enc0_bg, enc0_Wc, enc0_bc);
        cell_l1(h0, h1, enc1_Wg, enc1_bg, enc1_Wc, enc1_bc);
    }
    for (int t = 0; t < HH; ++t) {
        const float* xin = (t == 0) ? xzero : (out + (size_t)(t - 1) * BB * NN);
        cell_l0(xin, h0, dec0_Wg, dec0_bg, dec0_Wc, dec0_bc);
        cell_l1(h0, h1, dec1_Wg, dec1_bg, dec1_Wc, dec1_bc);
        proj_kernel<<<(RTOT + 255) / 256, 256, 0, stream>>>(h1, projW, projb,
                                                            out + (size_t)t * BB * NN);
    }
}